// Round 1
// baseline (1118.574 us; speedup 1.0000x reference)
//
#include <hip/hip_runtime.h>
#include <hip/hip_bf16.h>
#include <math.h>

#define N_NODES 100000
#define N_EDGES 3200000
#define ET (N_EDGES + N_NODES)
#define F_IN 128
#define HID 32
#define NCLS 40
#define NEG 0.2f

// ---------------- CSR build ----------------

__global__ void k_init_deg(int* __restrict__ deg) {
    int i = blockIdx.x * 256 + threadIdx.x;
    if (i < N_NODES) deg[i] = 1;  // self loop
}

__global__ void k_hist(const int* __restrict__ dst, int* __restrict__ deg) {
    int e = blockIdx.x * 256 + threadIdx.x;
    if (e < N_EDGES) atomicAdd(&deg[dst[e]], 1);
}

// block scans 1024 elements (256 thr x 4); writes local exclusive scan + block sum
__global__ void k_scan1(const int* __restrict__ deg, int* __restrict__ rs,
                        int* __restrict__ bsums) {
    __shared__ int sd[256];
    int t = threadIdx.x, b = blockIdx.x;
    int base = b * 1024 + t * 4;
    int v0 = 0, v1 = 0, v2 = 0, v3 = 0;
    if (base     < N_NODES) v0 = deg[base];
    if (base + 1 < N_NODES) v1 = deg[base + 1];
    if (base + 2 < N_NODES) v2 = deg[base + 2];
    if (base + 3 < N_NODES) v3 = deg[base + 3];
    int tsum = v0 + v1 + v2 + v3;
    sd[t] = tsum;
    __syncthreads();
    for (int off = 1; off < 256; off <<= 1) {
        int xx = (t >= off) ? sd[t - off] : 0;
        __syncthreads();
        sd[t] += xx;
        __syncthreads();
    }
    int texcl = sd[t] - tsum;  // exclusive prefix for this thread
    if (t == 255) bsums[b] = sd[255];
    if (base     < N_NODES) rs[base]     = texcl;
    if (base + 1 < N_NODES) rs[base + 1] = texcl + v0;
    if (base + 2 < N_NODES) rs[base + 2] = texcl + v0 + v1;
    if (base + 3 < N_NODES) rs[base + 3] = texcl + v0 + v1 + v2;
}

__global__ void k_scan2(const int* __restrict__ bsums, int* __restrict__ boffs, int nb) {
    __shared__ int sd[256];
    int t = threadIdx.x;
    int v = (t < nb) ? bsums[t] : 0;
    sd[t] = v;
    __syncthreads();
    for (int off = 1; off < 256; off <<= 1) {
        int xx = (t >= off) ? sd[t - off] : 0;
        __syncthreads();
        sd[t] += xx;
        __syncthreads();
    }
    if (t < nb) boffs[t] = sd[t] - v;
}

__global__ void k_scan3(int* __restrict__ rs, int* __restrict__ cursor,
                        const int* __restrict__ boffs) {
    int i = blockIdx.x * 256 + threadIdx.x;
    if (i < N_NODES) {
        int r = rs[i] + boffs[i >> 10];
        rs[i] = r;
        cursor[i] = r;
    }
}

__global__ void k_scatter(const int* __restrict__ src, const int* __restrict__ dst,
                          int* __restrict__ cursor, int* __restrict__ esrc) {
    int e = blockIdx.x * 256 + threadIdx.x;
    if (e < N_EDGES) {
        int d = dst[e];
        int pos = atomicAdd(&cursor[d], 1);
        esrc[pos] = src[e];
    } else if (e < ET) {
        int v = e - N_EDGES;
        int pos = atomicAdd(&cursor[v], 1);
        esrc[pos] = v;  // self loop
    }
}

// ---------------- Layer compute ----------------

// h1 = x @ W1 ; s1 = h1 . a_src ; d1 = h1 . a_dst   (8 nodes/block, 32 thr/node)
__global__ __launch_bounds__(256) void k_gemm1(
    const float* __restrict__ x, const float* __restrict__ W1,
    const float* __restrict__ a_s, const float* __restrict__ a_d,
    float* __restrict__ h1, float* __restrict__ s1, float* __restrict__ d1) {
    __shared__ float Ws[F_IN * HID];  // 16 KB
    int t = threadIdx.x;
    for (int i = t; i < F_IN * HID; i += 256) Ws[i] = W1[i];
    __syncthreads();
    int c = t & 31;
    int v = blockIdx.x * 8 + (t >> 5);
    const float4* x4 = (const float4*)(x + (size_t)v * F_IN);
    float acc = 0.f;
#pragma unroll
    for (int k4 = 0; k4 < F_IN / 4; k4++) {
        float4 xv = x4[k4];
        int k = k4 * 4;
        acc = fmaf(xv.x, Ws[(k + 0) * HID + c], acc);
        acc = fmaf(xv.y, Ws[(k + 1) * HID + c], acc);
        acc = fmaf(xv.z, Ws[(k + 2) * HID + c], acc);
        acc = fmaf(xv.w, Ws[(k + 3) * HID + c], acc);
    }
    h1[(size_t)v * HID + c] = acc;
    float p = acc * a_s[c];
    float q = acc * a_d[c];
    for (int mm = 16; mm >= 1; mm >>= 1) {
        p += __shfl_xor(p, mm, 32);
        q += __shfl_xor(q, mm, 32);
    }
    if (c == 0) { s1[v] = p; d1[v] = q; }
}

// per-dst online softmax aggregation, layer 1. 1 wave/node: 2 edges x 32 ch.
__global__ __launch_bounds__(256) void k_edge1(
    const int* __restrict__ rs, const int* __restrict__ deg, const int* __restrict__ esrc,
    const float* __restrict__ h1, const float* __restrict__ s1, const float* __restrict__ d1,
    const float* __restrict__ b1, float* __restrict__ hr) {
    int lane = threadIdx.x & 63;
    int wid = threadIdx.x >> 6;
    int v = blockIdx.x * 4 + wid;
    int esub = lane >> 5;
    int c = lane & 31;
    int start = rs[v];
    int cnt = deg[v];
    float dval = d1[v];
    float m = -INFINITY, den = 0.f, acc = 0.f;
    for (int t = esub; t < cnt; t += 2) {
        int s = esrc[start + t];
        float e = s1[s] + dval;
        e = (e >= 0.f) ? e : NEG * e;
        float hv = h1[(size_t)s * HID + c];
        if (e > m) {
            float sc = (m == -INFINITY) ? 0.f : __expf(m - e);
            den *= sc; acc *= sc; m = e;
        }
        float w = __expf(e - m);
        den += w;
        acc += w * hv;
    }
    // merge the two half-wave online-softmax states
    float mo = __shfl_xor(m, 32);
    float dn = __shfl_xor(den, 32);
    float ao = __shfl_xor(acc, 32);
    float M = fmaxf(m, mo);
    float wsf = (m == -INFINITY) ? 0.f : __expf(m - M);
    float wof = (mo == -INFINITY) ? 0.f : __expf(mo - M);
    den = den * wsf + dn * wof;
    acc = acc * wsf + ao * wof;
    if (esub == 0) {
        float o = acc / den + b1[c];
        hr[(size_t)v * HID + c] = fmaxf(o, 0.f);  // ReLU
    }
}

// h2 = hr @ W2 ; s2,d2. 8 nodes/block, 40 thr/node (320 threads = 5 waves)
__global__ __launch_bounds__(320) void k_gemm2(
    const float* __restrict__ hr, const float* __restrict__ W2,
    const float* __restrict__ a_s, const float* __restrict__ a_d,
    float* __restrict__ h2, float* __restrict__ s2, float* __restrict__ d2) {
    __shared__ float Ws[HID * NCLS];
    __shared__ float red_s[320], red_d[320];
    int t = threadIdx.x;
    for (int i = t; i < HID * NCLS; i += 320) Ws[i] = W2[i];
    __syncthreads();
    int c = t % NCLS;
    int v = blockIdx.x * 8 + t / NCLS;
    const float4* r4 = (const float4*)(hr + (size_t)v * HID);
    float acc = 0.f;
#pragma unroll
    for (int k4 = 0; k4 < HID / 4; k4++) {
        float4 rv = r4[k4];
        int k = k4 * 4;
        acc = fmaf(rv.x, Ws[(k + 0) * NCLS + c], acc);
        acc = fmaf(rv.y, Ws[(k + 1) * NCLS + c], acc);
        acc = fmaf(rv.z, Ws[(k + 2) * NCLS + c], acc);
        acc = fmaf(rv.w, Ws[(k + 3) * NCLS + c], acc);
    }
    h2[(size_t)v * NCLS + c] = acc;
    red_s[t] = acc * a_s[c];
    red_d[t] = acc * a_d[c];
    __syncthreads();
    if (c == 0) {
        float ss = 0.f, dd = 0.f;
        for (int j = 0; j < NCLS; j++) { ss += red_s[t + j]; dd += red_d[t + j]; }
        s2[v] = ss;
        d2[v] = dd;
    }
}

// per-dst online softmax aggregation layer 2 + bias + ReLU + log_softmax
__global__ __launch_bounds__(256) void k_edge2(
    const int* __restrict__ rs, const int* __restrict__ deg, const int* __restrict__ esrc,
    const float* __restrict__ h2, const float* __restrict__ s2, const float* __restrict__ d2,
    const float* __restrict__ b2, float* __restrict__ out) {
    int lane = threadIdx.x & 63;
    int wid = threadIdx.x >> 6;
    int v = blockIdx.x * 4 + wid;
    bool act = lane < NCLS;
    int start = rs[v];
    int cnt = deg[v];
    float dval = d2[v];
    float m = -INFINITY, den = 0.f, acc = 0.f;
    for (int t = 0; t < cnt; t++) {
        int s = esrc[start + t];
        float e = s2[s] + dval;
        e = (e >= 0.f) ? e : NEG * e;
        float hv = act ? h2[(size_t)s * NCLS + lane] : 0.f;
        if (e > m) {
            float sc = (m == -INFINITY) ? 0.f : __expf(m - e);
            den *= sc; acc *= sc; m = e;
        }
        float w = __expf(e - m);
        den += w;
        acc += w * hv;
    }
    float o = acc / den + (act ? b2[lane] : 0.f);
    o = fmaxf(o, 0.f);  // ReLU
    // log_softmax over the 40 channels (wave reduction; inactive lanes neutral)
    float z = act ? o : -INFINITY;
    float mx = z;
    for (int mm = 32; mm >= 1; mm >>= 1) mx = fmaxf(mx, __shfl_xor(mx, mm));
    float ex = act ? __expf(o - mx) : 0.f;
    float se = ex;
    for (int mm = 32; mm >= 1; mm >>= 1) se += __shfl_xor(se, mm);
    if (act) out[(size_t)v * NCLS + lane] = o - mx - logf(se);
}

// ---------------- launch ----------------

extern "C" void kernel_launch(void* const* d_in, const int* in_sizes, int n_in,
                              void* d_out, int out_size, void* d_ws, size_t ws_size,
                              hipStream_t stream) {
    (void)in_sizes; (void)n_in; (void)out_size; (void)ws_size;
    const float* x   = (const float*)d_in[0];
    const int*   ei  = (const int*)d_in[1];
    const float* W1  = (const float*)d_in[2];
    const float* as1 = (const float*)d_in[3];
    const float* ad1 = (const float*)d_in[4];
    const float* b1  = (const float*)d_in[5];
    const float* W2  = (const float*)d_in[6];
    const float* as2 = (const float*)d_in[7];
    const float* ad2 = (const float*)d_in[8];
    const float* b2  = (const float*)d_in[9];
    float* out = (float*)d_out;
    const int* srcA = ei;
    const int* dstA = ei + N_EDGES;

    char* w = (char*)d_ws;
    size_t off = 0;
    auto alloc = [&](size_t bytes) {
        char* p = w + off;
        off = (off + bytes + 255) & ~(size_t)255;
        return p;
    };
    int* esrc    = (int*)alloc((size_t)ET * 4);
    int* rs      = (int*)alloc((size_t)N_NODES * 4);
    int* deg     = (int*)alloc((size_t)N_NODES * 4);
    int* cursor  = (int*)alloc((size_t)N_NODES * 4);
    int* bsums   = (int*)alloc(256 * 4);
    int* boffs   = (int*)alloc(256 * 4);
    float* h1    = (float*)alloc((size_t)N_NODES * HID * 4);
    float* s1    = (float*)alloc((size_t)N_NODES * 4);
    float* d1    = (float*)alloc((size_t)N_NODES * 4);
    float* hrb   = (float*)alloc((size_t)N_NODES * HID * 4);
    float* h2    = (float*)alloc((size_t)N_NODES * NCLS * 4);
    float* s2    = (float*)alloc((size_t)N_NODES * 4);
    float* d2    = (float*)alloc((size_t)N_NODES * 4);

    int nb = (N_NODES + 1023) / 1024;  // 98
    hipLaunchKernelGGL(k_init_deg, dim3((N_NODES + 255) / 256), dim3(256), 0, stream, deg);
    hipLaunchKernelGGL(k_hist, dim3((N_EDGES + 255) / 256), dim3(256), 0, stream, dstA, deg);
    hipLaunchKernelGGL(k_scan1, dim3(nb), dim3(256), 0, stream, deg, rs, bsums);
    hipLaunchKernelGGL(k_scan2, dim3(1), dim3(256), 0, stream, bsums, boffs, nb);
    hipLaunchKernelGGL(k_scan3, dim3((N_NODES + 255) / 256), dim3(256), 0, stream, rs, cursor, boffs);
    hipLaunchKernelGGL(k_scatter, dim3((ET + 255) / 256), dim3(256), 0, stream, srcA, dstA, cursor, esrc);
    hipLaunchKernelGGL(k_gemm1, dim3(N_NODES / 8), dim3(256), 0, stream, x, W1, as1, ad1, h1, s1, d1);
    hipLaunchKernelGGL(k_edge1, dim3(N_NODES / 4), dim3(256), 0, stream, rs, deg, esrc, h1, s1, d1, b1, hrb);
    hipLaunchKernelGGL(k_gemm2, dim3(N_NODES / 8), dim3(320), 0, stream, hrb, W2, as2, ad2, h2, s2, d2);
    hipLaunchKernelGGL(k_edge2, dim3(N_NODES / 4), dim3(256), 0, stream, rs, deg, esrc, h2, s2, d2, b2, out);
}

// Round 2
// 850.152 us; speedup vs baseline: 1.3157x; 1.3157x over previous
//
#include <hip/hip_runtime.h>
#include <hip/hip_bf16.h>
#include <math.h>

#define N_NODES 100000
#define N_EDGES 3200000
#define ET (N_EDGES + N_NODES)
#define F_IN 128
#define HID 32
#define NCLS 40
#define NEG 0.2f

// ---------------- CSR build ----------------

__global__ void k_init_deg(int* __restrict__ deg) {
    int i = blockIdx.x * 256 + threadIdx.x;
    if (i < N_NODES) deg[i] = 1;  // self loop
}

__global__ void k_hist(const int* __restrict__ dst, int* __restrict__ deg) {
    int e = blockIdx.x * 256 + threadIdx.x;
    if (e < N_EDGES) atomicAdd(&deg[dst[e]], 1);
}

__global__ void k_scan1(const int* __restrict__ deg, int* __restrict__ rs,
                        int* __restrict__ bsums) {
    __shared__ int sd[256];
    int t = threadIdx.x, b = blockIdx.x;
    int base = b * 1024 + t * 4;
    int v0 = 0, v1 = 0, v2 = 0, v3 = 0;
    if (base     < N_NODES) v0 = deg[base];
    if (base + 1 < N_NODES) v1 = deg[base + 1];
    if (base + 2 < N_NODES) v2 = deg[base + 2];
    if (base + 3 < N_NODES) v3 = deg[base + 3];
    int tsum = v0 + v1 + v2 + v3;
    sd[t] = tsum;
    __syncthreads();
    for (int off = 1; off < 256; off <<= 1) {
        int xx = (t >= off) ? sd[t - off] : 0;
        __syncthreads();
        sd[t] += xx;
        __syncthreads();
    }
    int texcl = sd[t] - tsum;
    if (t == 255) bsums[b] = sd[255];
    if (base     < N_NODES) rs[base]     = texcl;
    if (base + 1 < N_NODES) rs[base + 1] = texcl + v0;
    if (base + 2 < N_NODES) rs[base + 2] = texcl + v0 + v1;
    if (base + 3 < N_NODES) rs[base + 3] = texcl + v0 + v1 + v2;
}

__global__ void k_scan2(const int* __restrict__ bsums, int* __restrict__ boffs, int nb) {
    __shared__ int sd[256];
    int t = threadIdx.x;
    int v = (t < nb) ? bsums[t] : 0;
    sd[t] = v;
    __syncthreads();
    for (int off = 1; off < 256; off <<= 1) {
        int xx = (t >= off) ? sd[t - off] : 0;
        __syncthreads();
        sd[t] += xx;
        __syncthreads();
    }
    if (t < nb) boffs[t] = sd[t] - v;
}

__global__ void k_scan3(int* __restrict__ rs, int* __restrict__ cursor,
                        const int* __restrict__ boffs) {
    int i = blockIdx.x * 256 + threadIdx.x;
    if (i < N_NODES) {
        int r = rs[i] + boffs[i >> 10];
        rs[i] = r;
        cursor[i] = r;
    }
}

__global__ void k_scatter(const int* __restrict__ src, const int* __restrict__ dst,
                          int* __restrict__ cursor, int* __restrict__ esrc) {
    int e = blockIdx.x * 256 + threadIdx.x;
    if (e < N_EDGES) {
        int d = dst[e];
        int pos = atomicAdd(&cursor[d], 1);
        esrc[pos] = src[e];
    } else if (e < ET) {
        int v = e - N_EDGES;
        int pos = atomicAdd(&cursor[v], 1);
        esrc[pos] = v;
    }
}

// ---------------- GEMMs ----------------

// h1 = x @ W1 ; s1 = h1 . a_src ; d1 = h1 . a_dst   (8 nodes/block)
__global__ __launch_bounds__(256) void k_gemm1(
    const float* __restrict__ x, const float* __restrict__ W1,
    const float* __restrict__ a_s, const float* __restrict__ a_d,
    float* __restrict__ h1, float* __restrict__ s1, float* __restrict__ d1) {
    __shared__ float Ws[F_IN * HID];   // 16 KB
    __shared__ float xs[8 * F_IN];     // 4 KB
    int t = threadIdx.x;
    const float4* W4 = (const float4*)W1;
    float4* Ws4 = (float4*)Ws;
#pragma unroll
    for (int i = 0; i < F_IN * HID / 4 / 256; i++)
        Ws4[t + i * 256] = W4[t + i * 256];
    ((float4*)xs)[t] = ((const float4*)(x + (size_t)blockIdx.x * 8 * F_IN))[t];
    __syncthreads();
    int c = t & 31, g = t >> 5;
    int v = blockIdx.x * 8 + g;
    const float4* xg4 = (const float4*)(xs + g * F_IN);
    float acc = 0.f;
#pragma unroll
    for (int k4 = 0; k4 < F_IN / 4; k4++) {
        float4 xv = xg4[k4];
        int k = k4 * 4;
        acc = fmaf(xv.x, Ws[(k + 0) * HID + c], acc);
        acc = fmaf(xv.y, Ws[(k + 1) * HID + c], acc);
        acc = fmaf(xv.z, Ws[(k + 2) * HID + c], acc);
        acc = fmaf(xv.w, Ws[(k + 3) * HID + c], acc);
    }
    h1[(size_t)v * HID + c] = acc;
    float p = acc * a_s[c];
    float q = acc * a_d[c];
    for (int mm = 16; mm >= 1; mm >>= 1) {
        p += __shfl_xor(p, mm, 32);
        q += __shfl_xor(q, mm, 32);
    }
    if (c == 0) { s1[v] = p; d1[v] = q; }
}

// h2 = hr @ W2 ; s2,d2. 8 nodes/block, 40 thr/node
__global__ __launch_bounds__(320) void k_gemm2(
    const float* __restrict__ hr, const float* __restrict__ W2,
    const float* __restrict__ a_s, const float* __restrict__ a_d,
    float* __restrict__ h2, float* __restrict__ s2, float* __restrict__ d2) {
    __shared__ float Ws[HID * NCLS];   // 1280 floats
    __shared__ float rsh[8 * HID];     // 256 floats
    __shared__ float red_s[320], red_d[320];
    int t = threadIdx.x;
    ((float4*)Ws)[t] = ((const float4*)W2)[t];  // 320 float4 = 1280 floats exact
    if (t < 64)
        ((float4*)rsh)[t] = ((const float4*)(hr + (size_t)blockIdx.x * 8 * HID))[t];
    __syncthreads();
    int c = t % NCLS;
    int g = t / NCLS;
    int v = blockIdx.x * 8 + g;
    const float* rrow = rsh + g * HID;
    float acc = 0.f;
#pragma unroll
    for (int k = 0; k < HID; k++)
        acc = fmaf(rrow[k], Ws[k * NCLS + c], acc);
    h2[(size_t)v * NCLS + c] = acc;
    red_s[t] = acc * a_s[c];
    red_d[t] = acc * a_d[c];
    __syncthreads();
    if (c == 0) {
        float ss = 0.f, dd = 0.f;
        for (int j = 0; j < NCLS; j++) { ss += red_s[t + j]; dd += red_d[t + j]; }
        s2[v] = ss;
        d2[v] = dd;
    }
}

// ---------------- softmax stats (shared by both layers) ----------------
// one wave per node; lanes edge-parallel; butterfly merge of (m, den)
__global__ __launch_bounds__(256) void k_stats(
    const int* __restrict__ rs, const int* __restrict__ deg, const int* __restrict__ esrc,
    const float* __restrict__ sarr, const float* __restrict__ darr,
    float* __restrict__ mS, float* __restrict__ idenS) {
    int lane = threadIdx.x & 63;
    int v = blockIdx.x * 4 + (threadIdx.x >> 6);
    int start = rs[v];
    int cnt = deg[v];
    float dval = darr[v];
    float m = -INFINITY, den = 0.f;
    for (int t = lane; t < cnt; t += 64) {
        int s = esrc[start + t];
        float e = sarr[s] + dval;
        e = (e >= 0.f) ? e : NEG * e;
        if (e > m) { den *= __expf(m - e); m = e; }   // expf(-inf)=0 handles first iter
        den += __expf(e - m);
    }
    for (int off = 32; off >= 1; off >>= 1) {
        float mo = __shfl_xor(m, off);
        float dno = __shfl_xor(den, off);
        float M = fmaxf(m, mo);
        float wa = (m == -INFINITY) ? 0.f : __expf(m - M);
        float wb = (mo == -INFINITY) ? 0.f : __expf(mo - M);
        den = den * wa + dno * wb;
        m = M;
    }
    if (lane == 0) { mS[v] = m; idenS[v] = 1.f / den; }
}

// ---------------- aggregation, layer 1 ----------------
// 1 wave/node; half-waves take even/odd edges; 4-deep unroll -> 8 row loads in flight
__global__ __launch_bounds__(256) void k_agg1(
    const int* __restrict__ rs, const int* __restrict__ deg, const int* __restrict__ esrc,
    const float* __restrict__ h1, const float* __restrict__ s1arr, const float* __restrict__ d1arr,
    const float* __restrict__ mS, const float* __restrict__ idenS,
    const float* __restrict__ b1, float* __restrict__ hr) {
    int lane = threadIdx.x & 63;
    int v = blockIdx.x * 4 + (threadIdx.x >> 6);
    int esub = lane >> 5;
    int c = lane & 31;
    int start = rs[v];
    int cnt = deg[v];
    float dval = d1arr[v];
    float mv = mS[v];
    float idv = idenS[v];
    float acc = 0.f;
    int t = esub;
    for (; t + 6 < cnt; t += 8) {
        int p = start + t;
        int sa = esrc[p];
        int sb = esrc[p + 2];
        int sc = esrc[p + 4];
        int sd = esrc[p + 6];
        float ea = s1arr[sa] + dval; ea = (ea >= 0.f) ? ea : NEG * ea;
        float eb = s1arr[sb] + dval; eb = (eb >= 0.f) ? eb : NEG * eb;
        float ec = s1arr[sc] + dval; ec = (ec >= 0.f) ? ec : NEG * ec;
        float ed = s1arr[sd] + dval; ed = (ed >= 0.f) ? ed : NEG * ed;
        float ha = h1[(size_t)sa * HID + c];
        float hb = h1[(size_t)sb * HID + c];
        float hc = h1[(size_t)sc * HID + c];
        float hd = h1[(size_t)sd * HID + c];
        float wa = __expf(ea - mv) * idv;
        float wb = __expf(eb - mv) * idv;
        float wc = __expf(ec - mv) * idv;
        float wd = __expf(ed - mv) * idv;
        acc = fmaf(wa, ha, acc);
        acc = fmaf(wb, hb, acc);
        acc = fmaf(wc, hc, acc);
        acc = fmaf(wd, hd, acc);
    }
    for (; t < cnt; t += 2) {
        int p = start + t;
        int sa = esrc[p];
        float ea = s1arr[sa] + dval; ea = (ea >= 0.f) ? ea : NEG * ea;
        float ha = h1[(size_t)sa * HID + c];
        acc = fmaf(__expf(ea - mv) * idv, ha, acc);
    }
    acc += __shfl_xor(acc, 32);
    if (esub == 0) {
        float o = acc + b1[c];
        hr[(size_t)v * HID + c] = fmaxf(o, 0.f);
    }
}

// ---------------- aggregation, layer 2 + bias + relu + log_softmax ----------------
// 8 nodes/block of 320; 40 threads per node; 4-deep unroll
__global__ __launch_bounds__(320) void k_agg2(
    const int* __restrict__ rs, const int* __restrict__ deg, const int* __restrict__ esrc,
    const float* __restrict__ h2, const float* __restrict__ s2arr, const float* __restrict__ d2arr,
    const float* __restrict__ mS, const float* __restrict__ idenS,
    const float* __restrict__ b2, float* __restrict__ out) {
    __shared__ float red[320];
    __shared__ float gm[8], gl[8];
    int t0 = threadIdx.x;
    int g = t0 / NCLS;
    int c = t0 % NCLS;
    int v = blockIdx.x * 8 + g;
    int start = rs[v];
    int cnt = deg[v];
    float dval = d2arr[v];
    float mv = mS[v];
    float idv = idenS[v];
    float acc = 0.f;
    int t = 0;
    for (; t + 3 < cnt; t += 4) {
        int p = start + t;
        int sa = esrc[p];
        int sb = esrc[p + 1];
        int sc = esrc[p + 2];
        int sd = esrc[p + 3];
        float ea = s2arr[sa] + dval; ea = (ea >= 0.f) ? ea : NEG * ea;
        float eb = s2arr[sb] + dval; eb = (eb >= 0.f) ? eb : NEG * eb;
        float ec = s2arr[sc] + dval; ec = (ec >= 0.f) ? ec : NEG * ec;
        float ed = s2arr[sd] + dval; ed = (ed >= 0.f) ? ed : NEG * ed;
        float ha = h2[(size_t)sa * NCLS + c];
        float hb = h2[(size_t)sb * NCLS + c];
        float hc = h2[(size_t)sc * NCLS + c];
        float hd = h2[(size_t)sd * NCLS + c];
        float wa = __expf(ea - mv) * idv;
        float wb = __expf(eb - mv) * idv;
        float wc = __expf(ec - mv) * idv;
        float wd = __expf(ed - mv) * idv;
        acc = fmaf(wa, ha, acc);
        acc = fmaf(wb, hb, acc);
        acc = fmaf(wc, hc, acc);
        acc = fmaf(wd, hd, acc);
    }
    for (; t < cnt; t++) {
        int p = start + t;
        int sa = esrc[p];
        float ea = s2arr[sa] + dval; ea = (ea >= 0.f) ? ea : NEG * ea;
        float ha = h2[(size_t)sa * NCLS + c];
        acc = fmaf(__expf(ea - mv) * idv, ha, acc);
    }
    float o = fmaxf(acc + b2[c], 0.f);
    red[t0] = o;
    __syncthreads();
    if (c == 0) {
        float mx = -INFINITY;
        for (int j = 0; j < NCLS; j++) mx = fmaxf(mx, red[g * NCLS + j]);
        float se = 0.f;
        for (int j = 0; j < NCLS; j++) se += __expf(red[g * NCLS + j] - mx);
        gm[g] = mx;
        gl[g] = logf(se);
    }
    __syncthreads();
    out[(size_t)v * NCLS + c] = o - gm[g] - gl[g];
}

// ---------------- launch ----------------

extern "C" void kernel_launch(void* const* d_in, const int* in_sizes, int n_in,
                              void* d_out, int out_size, void* d_ws, size_t ws_size,
                              hipStream_t stream) {
    (void)in_sizes; (void)n_in; (void)out_size; (void)ws_size;
    const float* x   = (const float*)d_in[0];
    const int*   ei  = (const int*)d_in[1];
    const float* W1  = (const float*)d_in[2];
    const float* as1 = (const float*)d_in[3];
    const float* ad1 = (const float*)d_in[4];
    const float* b1  = (const float*)d_in[5];
    const float* W2  = (const float*)d_in[6];
    const float* as2 = (const float*)d_in[7];
    const float* ad2 = (const float*)d_in[8];
    const float* b2  = (const float*)d_in[9];
    float* out = (float*)d_out;
    const int* srcA = ei;
    const int* dstA = ei + N_EDGES;

    char* w = (char*)d_ws;
    size_t off = 0;
    auto alloc = [&](size_t bytes) {
        char* p = w + off;
        off = (off + bytes + 255) & ~(size_t)255;
        return p;
    };
    int* esrc    = (int*)alloc((size_t)ET * 4);
    int* rs      = (int*)alloc((size_t)N_NODES * 4);
    int* deg     = (int*)alloc((size_t)N_NODES * 4);
    int* cursor  = (int*)alloc((size_t)N_NODES * 4);
    int* bsums   = (int*)alloc(256 * 4);
    int* boffs   = (int*)alloc(256 * 4);
    float* h1    = (float*)alloc((size_t)N_NODES * HID * 4);
    float* s1    = (float*)alloc((size_t)N_NODES * 4);
    float* d1    = (float*)alloc((size_t)N_NODES * 4);
    float* hrb   = (float*)alloc((size_t)N_NODES * HID * 4);
    float* h2    = (float*)alloc((size_t)N_NODES * NCLS * 4);
    float* s2    = (float*)alloc((size_t)N_NODES * 4);
    float* d2    = (float*)alloc((size_t)N_NODES * 4);
    float* mS    = (float*)alloc((size_t)N_NODES * 4);
    float* idenS = (float*)alloc((size_t)N_NODES * 4);

    int nb = (N_NODES + 1023) / 1024;
    hipLaunchKernelGGL(k_init_deg, dim3((N_NODES + 255) / 256), dim3(256), 0, stream, deg);
    hipLaunchKernelGGL(k_hist, dim3((N_EDGES + 255) / 256), dim3(256), 0, stream, dstA, deg);
    hipLaunchKernelGGL(k_scan1, dim3(nb), dim3(256), 0, stream, deg, rs, bsums);
    hipLaunchKernelGGL(k_scan2, dim3(1), dim3(256), 0, stream, bsums, boffs, nb);
    hipLaunchKernelGGL(k_scan3, dim3((N_NODES + 255) / 256), dim3(256), 0, stream, rs, cursor, boffs);
    hipLaunchKernelGGL(k_scatter, dim3((ET + 255) / 256), dim3(256), 0, stream, srcA, dstA, cursor, esrc);
    hipLaunchKernelGGL(k_gemm1, dim3(N_NODES / 8), dim3(256), 0, stream, x, W1, as1, ad1, h1, s1, d1);
    hipLaunchKernelGGL(k_stats, dim3(N_NODES / 4), dim3(256), 0, stream, rs, deg, esrc, s1, d1, mS, idenS);
    hipLaunchKernelGGL(k_agg1, dim3(N_NODES / 4), dim3(256), 0, stream, rs, deg, esrc, h1, s1, d1, mS, idenS, b1, hrb);
    hipLaunchKernelGGL(k_gemm2, dim3(N_NODES / 8), dim3(320), 0, stream, hrb, W2, as2, ad2, h2, s2, d2);
    hipLaunchKernelGGL(k_stats, dim3(N_NODES / 4), dim3(256), 0, stream, rs, deg, esrc, s2, d2, mS, idenS);
    hipLaunchKernelGGL(k_agg2, dim3(N_NODES / 8), dim3(320), 0, stream, rs, deg, esrc, h2, s2, d2, mS, idenS, b2, out);
}

// Round 3
// 523.110 us; speedup vs baseline: 2.1383x; 1.6252x over previous
//
#include <hip/hip_runtime.h>
#include <hip/hip_bf16.h>
#include <math.h>

#define N_NODES 100000
#define N_EDGES 3200000
#define ET (N_EDGES + N_NODES)
#define F_IN 128
#define HID 32
#define NCLS 40
#define NEG 0.2f

// bucket sort geometry
#define NB 782      // buckets of 128 dst-nodes: ceil(100000/128)
#define NBLK 782    // pass-A blocks: ceil(3.2M/4096)
#define CHUNK 4096  // edges per pass-A block
#define BCAP 6144   // max edges per bucket staged in LDS (mean 4092, sigma 64 -> 32 sigma)

// ---------------- Pass A: bucket histogram ----------------
__global__ __launch_bounds__(256) void kA_hist(const int* __restrict__ dst,
                                               int* __restrict__ Hm) {
    __shared__ int hist[NB];
    int t = threadIdx.x, k = blockIdx.x;
    for (int i = t; i < NB; i += 256) hist[i] = 0;
    __syncthreads();
    int base = k * CHUNK;
#pragma unroll
    for (int j = 0; j < CHUNK / 256; j++) {
        int e = base + j * 256 + t;
        if (e < N_EDGES) atomicAdd(&hist[dst[e] >> 7], 1);
    }
    __syncthreads();
    for (int i = t; i < NB; i += 256) Hm[i * NBLK + k] = hist[i];
}

// ---------------- generic exclusive scan (3 kernels) ----------------
__global__ void k_scan_a(const int* __restrict__ in, int* __restrict__ out,
                         int* __restrict__ bsums, int L) {
    __shared__ int sd[256];
    int t = threadIdx.x, b = blockIdx.x;
    int base = b * 1024 + t * 4;
    int v0 = 0, v1 = 0, v2 = 0, v3 = 0;
    if (base     < L) v0 = in[base];
    if (base + 1 < L) v1 = in[base + 1];
    if (base + 2 < L) v2 = in[base + 2];
    if (base + 3 < L) v3 = in[base + 3];
    int ts = v0 + v1 + v2 + v3;
    sd[t] = ts;
    __syncthreads();
    for (int off = 1; off < 256; off <<= 1) {
        int xx = (t >= off) ? sd[t - off] : 0;
        __syncthreads();
        sd[t] += xx;
        __syncthreads();
    }
    int ex = sd[t] - ts;
    if (t == 255) bsums[b] = sd[255];
    if (base     < L) out[base]     = ex;
    if (base + 1 < L) out[base + 1] = ex + v0;
    if (base + 2 < L) out[base + 2] = ex + v0 + v1;
    if (base + 3 < L) out[base + 3] = ex + v0 + v1 + v2;
}

__global__ void k_scan_b(const int* __restrict__ bsums, int* __restrict__ boffs, int nb) {
    __shared__ int sd[256];
    int t = threadIdx.x;
    int base = t * 4;
    int v0 = 0, v1 = 0, v2 = 0, v3 = 0;
    if (base     < nb) v0 = bsums[base];
    if (base + 1 < nb) v1 = bsums[base + 1];
    if (base + 2 < nb) v2 = bsums[base + 2];
    if (base + 3 < nb) v3 = bsums[base + 3];
    int ts = v0 + v1 + v2 + v3;
    sd[t] = ts;
    __syncthreads();
    for (int off = 1; off < 256; off <<= 1) {
        int xx = (t >= off) ? sd[t - off] : 0;
        __syncthreads();
        sd[t] += xx;
        __syncthreads();
    }
    int ex = sd[t] - ts;
    if (base     < nb) boffs[base]     = ex;
    if (base + 1 < nb) boffs[base + 1] = ex + v0;
    if (base + 2 < nb) boffs[base + 2] = ex + v0 + v1;
    if (base + 3 < nb) boffs[base + 3] = ex + v0 + v1 + v2;
}

__global__ void k_scan_c(int* __restrict__ out, const int* __restrict__ boffs, int L) {
    int i = blockIdx.x * 256 + threadIdx.x;
    if (i < L) out[i] += boffs[i >> 10];
}

// ---------------- Pass A: scatter into buckets (packed u32, LDS-reordered) ----------------
__global__ __launch_bounds__(256) void kA_scatter(
    const int* __restrict__ src, const int* __restrict__ dst,
    const int* __restrict__ Sx, unsigned int* __restrict__ tmp) {
    __shared__ int hist[NB];
    __shared__ int lofs[NB];
    __shared__ int cur[NB];
    __shared__ int tsum[256];
    __shared__ unsigned int stage[CHUNK];
    __shared__ int gpos[CHUNK];
    int t = threadIdx.x, k = blockIdx.x;
    for (int i = t; i < NB; i += 256) hist[i] = 0;
    __syncthreads();
    int base = k * CHUNK;
    int myd[16], mys[16];
#pragma unroll
    for (int j = 0; j < 16; j++) {
        int e = base + j * 256 + t;
        myd[j] = (e < N_EDGES) ? dst[e] : -1;
        mys[j] = (e < N_EDGES) ? src[e] : 0;
        if (myd[j] >= 0) atomicAdd(&hist[myd[j] >> 7], 1);
    }
    __syncthreads();
    // exclusive scan of hist[0..NB) -> lofs ; thread t owns bins [4t, 4t+4)
    int i0 = 4 * t;
    int h0 = (i0     < NB) ? hist[i0]     : 0;
    int h1 = (i0 + 1 < NB) ? hist[i0 + 1] : 0;
    int h2 = (i0 + 2 < NB) ? hist[i0 + 2] : 0;
    int h3 = (i0 + 3 < NB) ? hist[i0 + 3] : 0;
    int ts = h0 + h1 + h2 + h3;
    tsum[t] = ts;
    __syncthreads();
    for (int off = 1; off < 256; off <<= 1) {
        int xx = (t >= off) ? tsum[t - off] : 0;
        __syncthreads();
        tsum[t] += xx;
        __syncthreads();
    }
    int ex = tsum[t] - ts;
    if (i0     < NB) { lofs[i0]     = ex;               cur[i0]     = 0; }
    if (i0 + 1 < NB) { lofs[i0 + 1] = ex + h0;          cur[i0 + 1] = 0; }
    if (i0 + 2 < NB) { lofs[i0 + 2] = ex + h0 + h1;     cur[i0 + 2] = 0; }
    if (i0 + 3 < NB) { lofs[i0 + 3] = ex + h0 + h1 + h2; cur[i0 + 3] = 0; }
    __syncthreads();
#pragma unroll
    for (int j = 0; j < 16; j++) {
        if (myd[j] >= 0) {
            int bkt = myd[j] >> 7;
            int slot = lofs[bkt] + atomicAdd(&cur[bkt], 1);
            stage[slot] = ((unsigned int)(myd[j] & 127) << 17) | (unsigned int)mys[j];
            gpos[slot] = Sx[bkt * NBLK + k] + (slot - lofs[bkt]);
        }
    }
    __syncthreads();
    int nvalid = min(CHUNK, N_EDGES - base);
    for (int i = t; i < nvalid; i += 256) tmp[gpos[i]] = stage[i];
}

// ---------------- Pass B: per-bucket 128-bin counting sort in LDS ----------------
__global__ __launch_bounds__(256) void kB_sort(
    const unsigned int* __restrict__ tmp, const int* __restrict__ Sx,
    int* __restrict__ esrc, int* __restrict__ rs, int* __restrict__ deg) {
    __shared__ unsigned int stage[BCAP];
    __shared__ int ordered[BCAP + 128];
    __shared__ int cnt[128], lofs[128], cur[128], sc[128];
    int t = threadIdx.x, b = blockIdx.x;
    int myBase = Sx[b * NBLK];
    int nextBase = (b == NB - 1) ? N_EDGES : Sx[(b + 1) * NBLK];
    int cntE = nextBase - myBase;
    int nNodes = min(128, N_NODES - b * 128);
    if (t < 128) { cnt[t] = 0; cur[t] = 0; }
    __syncthreads();
    for (int i = t; i < cntE; i += 256) {
        unsigned int p = tmp[myBase + i];
        stage[i] = p;
        atomicAdd(&cnt[p >> 17], 1);
    }
    __syncthreads();
    // exclusive scan of (cnt[j]+1) over nNodes segments
    int val = 0;
    if (t < 128) { val = (t < nNodes) ? cnt[t] + 1 : 0; sc[t] = val; }
    __syncthreads();
    for (int off = 1; off < 128; off <<= 1) {
        int xx = 0;
        if (t < 128 && t >= off) xx = sc[t - off];
        __syncthreads();
        if (t < 128) sc[t] += xx;
        __syncthreads();
    }
    if (t < 128) lofs[t] = sc[t] - val;
    __syncthreads();
    // self-loop at each segment head
    if (t < nNodes) ordered[lofs[t]] = b * 128 + t;
    // place edges (order within segment irrelevant)
    for (int i = t; i < cntE; i += 256) {
        unsigned int p = stage[i];
        int n = p >> 17;
        int slot = lofs[n] + 1 + atomicAdd(&cur[n], 1);
        ordered[slot] = (int)(p & 0x1FFFF);
    }
    __syncthreads();
    int gb = myBase + b * 128;  // + prior buckets' self-loops (128 each)
    int totOut = cntE + nNodes;
    for (int i = t; i < totOut; i += 256) esrc[gb + i] = ordered[i];
    if (t < nNodes) {
        rs[b * 128 + t] = gb + lofs[t];
        deg[b * 128 + t] = cnt[t] + 1;
    }
}

// ---------------- GEMMs ----------------

__global__ __launch_bounds__(256) void k_gemm1(
    const float* __restrict__ x, const float* __restrict__ W1,
    const float* __restrict__ a_s, const float* __restrict__ a_d,
    float* __restrict__ h1, float* __restrict__ s1, float* __restrict__ d1) {
    __shared__ float Ws[F_IN * HID];
    __shared__ float xs[8 * F_IN];
    int t = threadIdx.x;
    const float4* W4 = (const float4*)W1;
    float4* Ws4 = (float4*)Ws;
#pragma unroll
    for (int i = 0; i < F_IN * HID / 4 / 256; i++)
        Ws4[t + i * 256] = W4[t + i * 256];
    ((float4*)xs)[t] = ((const float4*)(x + (size_t)blockIdx.x * 8 * F_IN))[t];
    __syncthreads();
    int c = t & 31, g = t >> 5;
    int v = blockIdx.x * 8 + g;
    const float4* xg4 = (const float4*)(xs + g * F_IN);
    float acc = 0.f;
#pragma unroll
    for (int k4 = 0; k4 < F_IN / 4; k4++) {
        float4 xv = xg4[k4];
        int k = k4 * 4;
        acc = fmaf(xv.x, Ws[(k + 0) * HID + c], acc);
        acc = fmaf(xv.y, Ws[(k + 1) * HID + c], acc);
        acc = fmaf(xv.z, Ws[(k + 2) * HID + c], acc);
        acc = fmaf(xv.w, Ws[(k + 3) * HID + c], acc);
    }
    h1[(size_t)v * HID + c] = acc;
    float p = acc * a_s[c];
    float q = acc * a_d[c];
    for (int mm = 16; mm >= 1; mm >>= 1) {
        p += __shfl_xor(p, mm, 32);
        q += __shfl_xor(q, mm, 32);
    }
    if (c == 0) { s1[v] = p; d1[v] = q; }
}

__global__ __launch_bounds__(320) void k_gemm2(
    const float* __restrict__ hr, const float* __restrict__ W2,
    const float* __restrict__ a_s, const float* __restrict__ a_d,
    float* __restrict__ h2, float* __restrict__ s2, float* __restrict__ d2) {
    __shared__ float Ws[HID * NCLS];
    __shared__ float rsh[8 * HID];
    __shared__ float red_s[320], red_d[320];
    int t = threadIdx.x;
    ((float4*)Ws)[t] = ((const float4*)W2)[t];
    if (t < 64)
        ((float4*)rsh)[t] = ((const float4*)(hr + (size_t)blockIdx.x * 8 * HID))[t];
    __syncthreads();
    int c = t % NCLS;
    int g = t / NCLS;
    int v = blockIdx.x * 8 + g;
    const float* rrow = rsh + g * HID;
    float acc = 0.f;
#pragma unroll
    for (int k = 0; k < HID; k++)
        acc = fmaf(rrow[k], Ws[k * NCLS + c], acc);
    h2[(size_t)v * NCLS + c] = acc;
    red_s[t] = acc * a_s[c];
    red_d[t] = acc * a_d[c];
    __syncthreads();
    if (c == 0) {
        float ss = 0.f, dd = 0.f;
        for (int j = 0; j < NCLS; j++) { ss += red_s[t + j]; dd += red_d[t + j]; }
        s2[v] = ss;
        d2[v] = dd;
    }
}

// ---------------- softmax stats ----------------
__global__ __launch_bounds__(256) void k_stats(
    const int* __restrict__ rs, const int* __restrict__ deg, const int* __restrict__ esrc,
    const float* __restrict__ sarr, const float* __restrict__ darr,
    float* __restrict__ mS, float* __restrict__ idenS) {
    int lane = threadIdx.x & 63;
    int v = blockIdx.x * 4 + (threadIdx.x >> 6);
    int start = rs[v];
    int cnt = deg[v];
    float dval = darr[v];
    float m = -INFINITY, den = 0.f;
    for (int t = lane; t < cnt; t += 64) {
        int s = esrc[start + t];
        float e = sarr[s] + dval;
        e = (e >= 0.f) ? e : NEG * e;
        if (e > m) { den *= __expf(m - e); m = e; }
        den += __expf(e - m);
    }
    for (int off = 32; off >= 1; off >>= 1) {
        float mo = __shfl_xor(m, off);
        float dno = __shfl_xor(den, off);
        float M = fmaxf(m, mo);
        float wa = (m == -INFINITY) ? 0.f : __expf(m - M);
        float wb = (mo == -INFINITY) ? 0.f : __expf(mo - M);
        den = den * wa + dno * wb;
        m = M;
    }
    if (lane == 0) { mS[v] = m; idenS[v] = 1.f / den; }
}

// ---------------- aggregation, layer 1 ----------------
__global__ __launch_bounds__(256) void k_agg1(
    const int* __restrict__ rs, const int* __restrict__ deg, const int* __restrict__ esrc,
    const float* __restrict__ h1, const float* __restrict__ s1arr, const float* __restrict__ d1arr,
    const float* __restrict__ mS, const float* __restrict__ idenS,
    const float* __restrict__ b1, float* __restrict__ hr) {
    int lane = threadIdx.x & 63;
    int v = blockIdx.x * 4 + (threadIdx.x >> 6);
    int esub = lane >> 5;
    int c = lane & 31;
    int start = rs[v];
    int cnt = deg[v];
    float dval = d1arr[v];
    float mv = mS[v];
    float idv = idenS[v];
    float acc = 0.f;
    int t = esub;
    for (; t + 6 < cnt; t += 8) {
        int p = start + t;
        int sa = esrc[p];
        int sb = esrc[p + 2];
        int sc = esrc[p + 4];
        int sd = esrc[p + 6];
        float ea = s1arr[sa] + dval; ea = (ea >= 0.f) ? ea : NEG * ea;
        float eb = s1arr[sb] + dval; eb = (eb >= 0.f) ? eb : NEG * eb;
        float ec = s1arr[sc] + dval; ec = (ec >= 0.f) ? ec : NEG * ec;
        float ed = s1arr[sd] + dval; ed = (ed >= 0.f) ? ed : NEG * ed;
        float ha = h1[(size_t)sa * HID + c];
        float hb = h1[(size_t)sb * HID + c];
        float hc = h1[(size_t)sc * HID + c];
        float hd = h1[(size_t)sd * HID + c];
        float wa = __expf(ea - mv) * idv;
        float wb = __expf(eb - mv) * idv;
        float wc = __expf(ec - mv) * idv;
        float wd = __expf(ed - mv) * idv;
        acc = fmaf(wa, ha, acc);
        acc = fmaf(wb, hb, acc);
        acc = fmaf(wc, hc, acc);
        acc = fmaf(wd, hd, acc);
    }
    for (; t < cnt; t += 2) {
        int p = start + t;
        int sa = esrc[p];
        float ea = s1arr[sa] + dval; ea = (ea >= 0.f) ? ea : NEG * ea;
        float ha = h1[(size_t)sa * HID + c];
        acc = fmaf(__expf(ea - mv) * idv, ha, acc);
    }
    acc += __shfl_xor(acc, 32);
    if (esub == 0) {
        float o = acc + b1[c];
        hr[(size_t)v * HID + c] = fmaxf(o, 0.f);
    }
}

// ---------------- aggregation, layer 2 + bias + relu + log_softmax ----------------
__global__ __launch_bounds__(320) void k_agg2(
    const int* __restrict__ rs, const int* __restrict__ deg, const int* __restrict__ esrc,
    const float* __restrict__ h2, const float* __restrict__ s2arr, const float* __restrict__ d2arr,
    const float* __restrict__ mS, const float* __restrict__ idenS,
    const float* __restrict__ b2, float* __restrict__ out) {
    __shared__ float red[320];
    __shared__ float gm[8], gl[8];
    int t0 = threadIdx.x;
    int g = t0 / NCLS;
    int c = t0 % NCLS;
    int v = blockIdx.x * 8 + g;
    int start = rs[v];
    int cnt = deg[v];
    float dval = d2arr[v];
    float mv = mS[v];
    float idv = idenS[v];
    float acc = 0.f;
    int t = 0;
    for (; t + 3 < cnt; t += 4) {
        int p = start + t;
        int sa = esrc[p];
        int sb = esrc[p + 1];
        int sc = esrc[p + 2];
        int sd = esrc[p + 3];
        float ea = s2arr[sa] + dval; ea = (ea >= 0.f) ? ea : NEG * ea;
        float eb = s2arr[sb] + dval; eb = (eb >= 0.f) ? eb : NEG * eb;
        float ec = s2arr[sc] + dval; ec = (ec >= 0.f) ? ec : NEG * ec;
        float ed = s2arr[sd] + dval; ed = (ed >= 0.f) ? ed : NEG * ed;
        float ha = h2[(size_t)sa * NCLS + c];
        float hb = h2[(size_t)sb * NCLS + c];
        float hc = h2[(size_t)sc * NCLS + c];
        float hd = h2[(size_t)sd * NCLS + c];
        float wa = __expf(ea - mv) * idv;
        float wb = __expf(eb - mv) * idv;
        float wc = __expf(ec - mv) * idv;
        float wd = __expf(ed - mv) * idv;
        acc = fmaf(wa, ha, acc);
        acc = fmaf(wb, hb, acc);
        acc = fmaf(wc, hc, acc);
        acc = fmaf(wd, hd, acc);
    }
    for (; t < cnt; t++) {
        int p = start + t;
        int sa = esrc[p];
        float ea = s2arr[sa] + dval; ea = (ea >= 0.f) ? ea : NEG * ea;
        float ha = h2[(size_t)sa * NCLS + c];
        acc = fmaf(__expf(ea - mv) * idv, ha, acc);
    }
    float o = fmaxf(acc + b2[c], 0.f);
    red[t0] = o;
    __syncthreads();
    if (c == 0) {
        float mx = -INFINITY;
        for (int j = 0; j < NCLS; j++) mx = fmaxf(mx, red[g * NCLS + j]);
        float se = 0.f;
        for (int j = 0; j < NCLS; j++) se += __expf(red[g * NCLS + j] - mx);
        gm[g] = mx;
        gl[g] = logf(se);
    }
    __syncthreads();
    out[(size_t)v * NCLS + c] = o - gm[g] - gl[g];
}

// ---------------- launch ----------------

extern "C" void kernel_launch(void* const* d_in, const int* in_sizes, int n_in,
                              void* d_out, int out_size, void* d_ws, size_t ws_size,
                              hipStream_t stream) {
    (void)in_sizes; (void)n_in; (void)out_size; (void)ws_size;
    const float* x   = (const float*)d_in[0];
    const int*   ei  = (const int*)d_in[1];
    const float* W1  = (const float*)d_in[2];
    const float* as1 = (const float*)d_in[3];
    const float* ad1 = (const float*)d_in[4];
    const float* b1  = (const float*)d_in[5];
    const float* W2  = (const float*)d_in[6];
    const float* as2 = (const float*)d_in[7];
    const float* ad2 = (const float*)d_in[8];
    const float* b2  = (const float*)d_in[9];
    float* out = (float*)d_out;
    const int* srcA = ei;
    const int* dstA = ei + N_EDGES;

    char* w = (char*)d_ws;
    size_t off = 0;
    auto alloc = [&](size_t bytes) {
        char* p = w + off;
        off = (off + bytes + 255) & ~(size_t)255;
        return p;
    };
    int* esrc    = (int*)alloc((size_t)ET * 4);
    int* rs      = (int*)alloc((size_t)N_NODES * 4);
    int* deg     = (int*)alloc((size_t)N_NODES * 4);
    float* h1    = (float*)alloc((size_t)N_NODES * HID * 4);   // Hm/Sx alias here (dead before gemm1)
    float* s1    = (float*)alloc((size_t)N_NODES * 4);
    float* d1    = (float*)alloc((size_t)N_NODES * 4);
    float* hrb   = (float*)alloc((size_t)N_NODES * HID * 4);
    float* h2    = (float*)alloc((size_t)N_NODES * NCLS * 4);  // tmp aliases here (dead before gemm2)
    float* s2    = (float*)alloc((size_t)N_NODES * 4);
    float* d2    = (float*)alloc((size_t)N_NODES * 4);
    float* mS    = (float*)alloc((size_t)N_NODES * 4);
    float* idenS = (float*)alloc((size_t)N_NODES * 4);
    int* bsums   = (int*)alloc(1024 * 4);
    int* boffs   = (int*)alloc(1024 * 4);

    const int L = NB * NBLK;                 // 611524
    int* Hm = (int*)h1;                      // 2.45 MB
    int* Sx = Hm + ((L + 63) & ~63);         // 2.45 MB (both fit in h1's 12.8 MB)
    unsigned int* tmp = (unsigned int*)h2;   // 12.8 MB fits in h2's 16 MB

    int nb1 = (L + 1023) / 1024;             // 598
    hipLaunchKernelGGL(kA_hist, dim3(NBLK), dim3(256), 0, stream, dstA, Hm);
    hipLaunchKernelGGL(k_scan_a, dim3(nb1), dim3(256), 0, stream, Hm, Sx, bsums, L);
    hipLaunchKernelGGL(k_scan_b, dim3(1), dim3(256), 0, stream, bsums, boffs, nb1);
    hipLaunchKernelGGL(k_scan_c, dim3((L + 255) / 256), dim3(256), 0, stream, Sx, boffs, L);
    hipLaunchKernelGGL(kA_scatter, dim3(NBLK), dim3(256), 0, stream, srcA, dstA, Sx, tmp);
    hipLaunchKernelGGL(kB_sort, dim3(NB), dim3(256), 0, stream, tmp, Sx, esrc, rs, deg);

    hipLaunchKernelGGL(k_gemm1, dim3(N_NODES / 8), dim3(256), 0, stream, x, W1, as1, ad1, h1, s1, d1);
    hipLaunchKernelGGL(k_stats, dim3(N_NODES / 4), dim3(256), 0, stream, rs, deg, esrc, s1, d1, mS, idenS);
    hipLaunchKernelGGL(k_agg1, dim3(N_NODES / 4), dim3(256), 0, stream, rs, deg, esrc, h1, s1, d1, mS, idenS, b1, hrb);
    hipLaunchKernelGGL(k_gemm2, dim3(N_NODES / 8), dim3(320), 0, stream, hrb, W2, as2, ad2, h2, s2, d2);
    hipLaunchKernelGGL(k_stats, dim3(N_NODES / 4), dim3(256), 0, stream, rs, deg, esrc, s2, d2, mS, idenS);
    hipLaunchKernelGGL(k_agg2, dim3(N_NODES / 8), dim3(320), 0, stream, rs, deg, esrc, h2, s2, d2, mS, idenS, b2, out);
}

// Round 4
// 512.501 us; speedup vs baseline: 2.1826x; 1.0207x over previous
//
#include <hip/hip_runtime.h>
#include <hip/hip_bf16.h>
#include <hip/hip_fp16.h>
#include <math.h>

#define N_NODES 100000
#define N_EDGES 3200000
#define ET (N_EDGES + N_NODES)
#define F_IN 128
#define HID 32
#define NCLS 40
#define NEG 0.2f

// bucket sort geometry
#define NB 782      // buckets of 128 dst-nodes: ceil(100000/128)
#define NBLK 782    // pass-A blocks: ceil(3.2M/4096)
#define CHUNK 4096  // edges per pass-A block
#define BCAP 6144   // max edges per bucket staged in LDS

// ---------------- Pass A: bucket histogram ----------------
__global__ __launch_bounds__(256) void kA_hist(const int* __restrict__ dst,
                                               int* __restrict__ Hm) {
    __shared__ int hist[NB];
    int t = threadIdx.x, k = blockIdx.x;
    for (int i = t; i < NB; i += 256) hist[i] = 0;
    __syncthreads();
    int base = k * CHUNK;
#pragma unroll
    for (int j = 0; j < CHUNK / 256; j++) {
        int e = base + j * 256 + t;
        if (e < N_EDGES) atomicAdd(&hist[dst[e] >> 7], 1);
    }
    __syncthreads();
    for (int i = t; i < NB; i += 256) Hm[i * NBLK + k] = hist[i];
}

// ---------------- generic exclusive scan (3 kernels) ----------------
__global__ void k_scan_a(const int* __restrict__ in, int* __restrict__ out,
                         int* __restrict__ bsums, int L) {
    __shared__ int sd[256];
    int t = threadIdx.x, b = blockIdx.x;
    int base = b * 1024 + t * 4;
    int v0 = 0, v1 = 0, v2 = 0, v3 = 0;
    if (base     < L) v0 = in[base];
    if (base + 1 < L) v1 = in[base + 1];
    if (base + 2 < L) v2 = in[base + 2];
    if (base + 3 < L) v3 = in[base + 3];
    int ts = v0 + v1 + v2 + v3;
    sd[t] = ts;
    __syncthreads();
    for (int off = 1; off < 256; off <<= 1) {
        int xx = (t >= off) ? sd[t - off] : 0;
        __syncthreads();
        sd[t] += xx;
        __syncthreads();
    }
    int ex = sd[t] - ts;
    if (t == 255) bsums[b] = sd[255];
    if (base     < L) out[base]     = ex;
    if (base + 1 < L) out[base + 1] = ex + v0;
    if (base + 2 < L) out[base + 2] = ex + v0 + v1;
    if (base + 3 < L) out[base + 3] = ex + v0 + v1 + v2;
}

__global__ void k_scan_b(const int* __restrict__ bsums, int* __restrict__ boffs, int nb) {
    __shared__ int sd[256];
    int t = threadIdx.x;
    int base = t * 4;
    int v0 = 0, v1 = 0, v2 = 0, v3 = 0;
    if (base     < nb) v0 = bsums[base];
    if (base + 1 < nb) v1 = bsums[base + 1];
    if (base + 2 < nb) v2 = bsums[base + 2];
    if (base + 3 < nb) v3 = bsums[base + 3];
    int ts = v0 + v1 + v2 + v3;
    sd[t] = ts;
    __syncthreads();
    for (int off = 1; off < 256; off <<= 1) {
        int xx = (t >= off) ? sd[t - off] : 0;
        __syncthreads();
        sd[t] += xx;
        __syncthreads();
    }
    int ex = sd[t] - ts;
    if (base     < nb) boffs[base]     = ex;
    if (base + 1 < nb) boffs[base + 1] = ex + v0;
    if (base + 2 < nb) boffs[base + 2] = ex + v0 + v1;
    if (base + 3 < nb) boffs[base + 3] = ex + v0 + v1 + v2;
}

__global__ void k_scan_c(int* __restrict__ out, const int* __restrict__ boffs, int L) {
    int i = blockIdx.x * 256 + threadIdx.x;
    if (i < L) out[i] += boffs[i >> 10];
}

// ---------------- Pass A: scatter into buckets ----------------
__global__ __launch_bounds__(256) void kA_scatter(
    const int* __restrict__ src, const int* __restrict__ dst,
    const int* __restrict__ Sx, unsigned int* __restrict__ tmp) {
    __shared__ int hist[NB];
    __shared__ int lofs[NB];
    __shared__ int cur[NB];
    __shared__ int tsum[256];
    __shared__ unsigned int stage[CHUNK];
    __shared__ int gpos[CHUNK];
    int t = threadIdx.x, k = blockIdx.x;
    for (int i = t; i < NB; i += 256) hist[i] = 0;
    __syncthreads();
    int base = k * CHUNK;
    int myd[16], mys[16];
#pragma unroll
    for (int j = 0; j < 16; j++) {
        int e = base + j * 256 + t;
        myd[j] = (e < N_EDGES) ? dst[e] : -1;
        mys[j] = (e < N_EDGES) ? src[e] : 0;
        if (myd[j] >= 0) atomicAdd(&hist[myd[j] >> 7], 1);
    }
    __syncthreads();
    int i0 = 4 * t;
    int h0 = (i0     < NB) ? hist[i0]     : 0;
    int h1 = (i0 + 1 < NB) ? hist[i0 + 1] : 0;
    int h2 = (i0 + 2 < NB) ? hist[i0 + 2] : 0;
    int h3 = (i0 + 3 < NB) ? hist[i0 + 3] : 0;
    int ts = h0 + h1 + h2 + h3;
    tsum[t] = ts;
    __syncthreads();
    for (int off = 1; off < 256; off <<= 1) {
        int xx = (t >= off) ? tsum[t - off] : 0;
        __syncthreads();
        tsum[t] += xx;
        __syncthreads();
    }
    int ex = tsum[t] - ts;
    if (i0     < NB) { lofs[i0]     = ex;                cur[i0]     = 0; }
    if (i0 + 1 < NB) { lofs[i0 + 1] = ex + h0;           cur[i0 + 1] = 0; }
    if (i0 + 2 < NB) { lofs[i0 + 2] = ex + h0 + h1;      cur[i0 + 2] = 0; }
    if (i0 + 3 < NB) { lofs[i0 + 3] = ex + h0 + h1 + h2; cur[i0 + 3] = 0; }
    __syncthreads();
#pragma unroll
    for (int j = 0; j < 16; j++) {
        if (myd[j] >= 0) {
            int bkt = myd[j] >> 7;
            int slot = lofs[bkt] + atomicAdd(&cur[bkt], 1);
            stage[slot] = ((unsigned int)(myd[j] & 127) << 17) | (unsigned int)mys[j];
            gpos[slot] = Sx[bkt * NBLK + k] + (slot - lofs[bkt]);
        }
    }
    __syncthreads();
    int nvalid = min(CHUNK, N_EDGES - base);
    for (int i = t; i < nvalid; i += 256) tmp[gpos[i]] = stage[i];
}

// ---------------- Pass B: per-bucket 128-bin counting sort in LDS ----------------
__global__ __launch_bounds__(256) void kB_sort(
    const unsigned int* __restrict__ tmp, const int* __restrict__ Sx,
    int* __restrict__ esrc, int* __restrict__ rs, int* __restrict__ deg) {
    __shared__ unsigned int stage[BCAP];
    __shared__ int ordered[BCAP + 128];
    __shared__ int cnt[128], lofs[128], cur[128], sc[128];
    int t = threadIdx.x, b = blockIdx.x;
    int myBase = Sx[b * NBLK];
    int nextBase = (b == NB - 1) ? N_EDGES : Sx[(b + 1) * NBLK];
    int cntE = nextBase - myBase;
    int nNodes = min(128, N_NODES - b * 128);
    if (t < 128) { cnt[t] = 0; cur[t] = 0; }
    __syncthreads();
    for (int i = t; i < cntE; i += 256) {
        unsigned int p = tmp[myBase + i];
        stage[i] = p;
        atomicAdd(&cnt[p >> 17], 1);
    }
    __syncthreads();
    int val = 0;
    if (t < 128) { val = (t < nNodes) ? cnt[t] + 1 : 0; sc[t] = val; }
    __syncthreads();
    for (int off = 1; off < 128; off <<= 1) {
        int xx = 0;
        if (t < 128 && t >= off) xx = sc[t - off];
        __syncthreads();
        if (t < 128) sc[t] += xx;
        __syncthreads();
    }
    if (t < 128) lofs[t] = sc[t] - val;
    __syncthreads();
    if (t < nNodes) ordered[lofs[t]] = b * 128 + t;
    for (int i = t; i < cntE; i += 256) {
        unsigned int p = stage[i];
        int n = p >> 17;
        int slot = lofs[n] + 1 + atomicAdd(&cur[n], 1);
        ordered[slot] = (int)(p & 0x1FFFF);
    }
    __syncthreads();
    int gb = myBase + b * 128;
    int totOut = cntE + nNodes;
    for (int i = t; i < totOut; i += 256) esrc[gb + i] = ordered[i];
    if (t < nNodes) {
        rs[b * 128 + t] = gb + lofs[t];
        deg[b * 128 + t] = cnt[t] + 1;
    }
}

// ---------------- GEMMs ----------------

// h1(fp16) = x @ W1 ; s1,d1 fp32
__global__ __launch_bounds__(256) void k_gemm1(
    const float* __restrict__ x, const float* __restrict__ W1,
    const float* __restrict__ a_s, const float* __restrict__ a_d,
    __half* __restrict__ h1h, float* __restrict__ s1, float* __restrict__ d1) {
    __shared__ float Ws[F_IN * HID];
    __shared__ float xs[8 * F_IN];
    int t = threadIdx.x;
    const float4* W4 = (const float4*)W1;
    float4* Ws4 = (float4*)Ws;
#pragma unroll
    for (int i = 0; i < F_IN * HID / 4 / 256; i++)
        Ws4[t + i * 256] = W4[t + i * 256];
    ((float4*)xs)[t] = ((const float4*)(x + (size_t)blockIdx.x * 8 * F_IN))[t];
    __syncthreads();
    int c = t & 31, g = t >> 5;
    int v = blockIdx.x * 8 + g;
    const float4* xg4 = (const float4*)(xs + g * F_IN);
    float acc = 0.f;
#pragma unroll
    for (int k4 = 0; k4 < F_IN / 4; k4++) {
        float4 xv = xg4[k4];
        int k = k4 * 4;
        acc = fmaf(xv.x, Ws[(k + 0) * HID + c], acc);
        acc = fmaf(xv.y, Ws[(k + 1) * HID + c], acc);
        acc = fmaf(xv.z, Ws[(k + 2) * HID + c], acc);
        acc = fmaf(xv.w, Ws[(k + 3) * HID + c], acc);
    }
    h1h[(size_t)v * HID + c] = __float2half(acc);
    float p = acc * a_s[c];
    float q = acc * a_d[c];
    for (int mm = 16; mm >= 1; mm >>= 1) {
        p += __shfl_xor(p, mm, 32);
        q += __shfl_xor(q, mm, 32);
    }
    if (c == 0) { s1[v] = p; d1[v] = q; }
}

// h2 = hr @ W2 -> split fp16 tables h2a (32ch) + h2b (8ch); s2,d2 fp32
__global__ __launch_bounds__(320) void k_gemm2(
    const float* __restrict__ hr, const float* __restrict__ W2,
    const float* __restrict__ a_s, const float* __restrict__ a_d,
    __half* __restrict__ h2a, __half* __restrict__ h2b,
    float* __restrict__ s2, float* __restrict__ d2) {
    __shared__ float Ws[HID * NCLS];
    __shared__ float rsh[8 * HID];
    __shared__ float red_s[320], red_d[320];
    int t = threadIdx.x;
    ((float4*)Ws)[t] = ((const float4*)W2)[t];
    if (t < 64)
        ((float4*)rsh)[t] = ((const float4*)(hr + (size_t)blockIdx.x * 8 * HID))[t];
    __syncthreads();
    int c = t % NCLS;
    int g = t / NCLS;
    int v = blockIdx.x * 8 + g;
    const float* rrow = rsh + g * HID;
    float acc = 0.f;
#pragma unroll
    for (int k = 0; k < HID; k++)
        acc = fmaf(rrow[k], Ws[k * NCLS + c], acc);
    if (c < 32) h2a[(size_t)v * 32 + c] = __float2half(acc);
    else        h2b[(size_t)v * 8 + (c - 32)] = __float2half(acc);
    red_s[t] = acc * a_s[c];
    red_d[t] = acc * a_d[c];
    __syncthreads();
    if (c == 0) {
        float ss = 0.f, dd = 0.f;
        for (int j = 0; j < NCLS; j++) { ss += red_s[t + j]; dd += red_d[t + j]; }
        s2[v] = ss;
        d2[v] = dd;
    }
}

// ---------------- softmax stats ----------------
__global__ __launch_bounds__(256) void k_stats(
    const int* __restrict__ rs, const int* __restrict__ deg, const int* __restrict__ esrc,
    const float* __restrict__ sarr, const float* __restrict__ darr,
    float* __restrict__ mS, float* __restrict__ idenS) {
    int lane = threadIdx.x & 63;
    int v = blockIdx.x * 4 + (threadIdx.x >> 6);
    int start = rs[v];
    int cnt = deg[v];
    float dval = darr[v];
    float m = -INFINITY, den = 0.f;
    for (int t = lane; t < cnt; t += 64) {
        int s = esrc[start + t];
        float e = sarr[s] + dval;
        e = (e >= 0.f) ? e : NEG * e;
        if (e > m) { den *= __expf(m - e); m = e; }
        den += __expf(e - m);
    }
    for (int off = 32; off >= 1; off >>= 1) {
        float mo = __shfl_xor(m, off);
        float dno = __shfl_xor(den, off);
        float M = fmaxf(m, mo);
        float wa = (m == -INFINITY) ? 0.f : __expf(m - M);
        float wb = (mo == -INFINITY) ? 0.f : __expf(mo - M);
        den = den * wa + dno * wb;
        m = M;
    }
    if (lane == 0) { mS[v] = m; idenS[v] = 1.f / den; }
}

// ---------------- aggregation, layer 1 (fp16 h-table, 1 line/edge) ----------------
__global__ __launch_bounds__(256) void k_agg1(
    const int* __restrict__ rs, const int* __restrict__ deg, const int* __restrict__ esrc,
    const __half* __restrict__ h1h, const float* __restrict__ s1arr, const float* __restrict__ d1arr,
    const float* __restrict__ mS, const float* __restrict__ idenS,
    const float* __restrict__ b1, float* __restrict__ hr) {
    int lane = threadIdx.x & 63;
    int v = blockIdx.x * 4 + (threadIdx.x >> 6);
    int esub = lane >> 5;
    int c = lane & 31;
    int start = rs[v];
    int cnt = deg[v];
    float dval = d1arr[v];
    float mv = mS[v];
    float idv = idenS[v];
    float acc = 0.f;
    int t = esub;
    for (; t + 6 < cnt; t += 8) {
        int p = start + t;
        int sa = esrc[p];
        int sb = esrc[p + 2];
        int sc = esrc[p + 4];
        int sd = esrc[p + 6];
        float ea = s1arr[sa] + dval; ea = (ea >= 0.f) ? ea : NEG * ea;
        float eb = s1arr[sb] + dval; eb = (eb >= 0.f) ? eb : NEG * eb;
        float ec = s1arr[sc] + dval; ec = (ec >= 0.f) ? ec : NEG * ec;
        float ed = s1arr[sd] + dval; ed = (ed >= 0.f) ? ed : NEG * ed;
        float ha = __half2float(h1h[(size_t)sa * HID + c]);
        float hb = __half2float(h1h[(size_t)sb * HID + c]);
        float hc = __half2float(h1h[(size_t)sc * HID + c]);
        float hd = __half2float(h1h[(size_t)sd * HID + c]);
        float wa = __expf(ea - mv) * idv;
        float wb = __expf(eb - mv) * idv;
        float wc = __expf(ec - mv) * idv;
        float wd = __expf(ed - mv) * idv;
        acc = fmaf(wa, ha, acc);
        acc = fmaf(wb, hb, acc);
        acc = fmaf(wc, hc, acc);
        acc = fmaf(wd, hd, acc);
    }
    for (; t < cnt; t += 2) {
        int p = start + t;
        int sa = esrc[p];
        float ea = s1arr[sa] + dval; ea = (ea >= 0.f) ? ea : NEG * ea;
        float ha = __half2float(h1h[(size_t)sa * HID + c]);
        acc = fmaf(__expf(ea - mv) * idv, ha, acc);
    }
    acc += __shfl_xor(acc, 32);
    if (esub == 0) {
        float o = acc + b1[c];
        hr[(size_t)v * HID + c] = fmaxf(o, 0.f);
    }
}

// ---------------- aggregation, layer 2 (split fp16 tables) + log_softmax ----------------
__global__ __launch_bounds__(320) void k_agg2(
    const int* __restrict__ rs, const int* __restrict__ deg, const int* __restrict__ esrc,
    const __half* __restrict__ h2a, const __half* __restrict__ h2b,
    const float* __restrict__ s2arr, const float* __restrict__ d2arr,
    const float* __restrict__ mS, const float* __restrict__ idenS,
    const float* __restrict__ b2, float* __restrict__ out) {
    __shared__ float red[320];
    __shared__ float gm[8], gl[8];
    int t0 = threadIdx.x;
    int g = t0 / NCLS;
    int c = t0 % NCLS;
    int v = blockIdx.x * 8 + g;
    int start = rs[v];
    int cnt = deg[v];
    float dval = d2arr[v];
    float mv = mS[v];
    float idv = idenS[v];
    // per-lane table base/stride select (branchless gather from split tables)
    const __half* tab = (c < 32) ? h2a : h2b;
    int stride = (c < 32) ? 32 : 8;
    int cc = (c < 32) ? c : (c - 32);
    float acc = 0.f;
    int t = 0;
    for (; t + 3 < cnt; t += 4) {
        int p = start + t;
        int sa = esrc[p];
        int sb = esrc[p + 1];
        int sc = esrc[p + 2];
        int sd = esrc[p + 3];
        float ea = s2arr[sa] + dval; ea = (ea >= 0.f) ? ea : NEG * ea;
        float eb = s2arr[sb] + dval; eb = (eb >= 0.f) ? eb : NEG * eb;
        float ec = s2arr[sc] + dval; ec = (ec >= 0.f) ? ec : NEG * ec;
        float ed = s2arr[sd] + dval; ed = (ed >= 0.f) ? ed : NEG * ed;
        float ha = __half2float(tab[(size_t)sa * stride + cc]);
        float hb = __half2float(tab[(size_t)sb * stride + cc]);
        float hc = __half2float(tab[(size_t)sc * stride + cc]);
        float hd = __half2float(tab[(size_t)sd * stride + cc]);
        float wa = __expf(ea - mv) * idv;
        float wb = __expf(eb - mv) * idv;
        float wc = __expf(ec - mv) * idv;
        float wd = __expf(ed - mv) * idv;
        acc = fmaf(wa, ha, acc);
        acc = fmaf(wb, hb, acc);
        acc = fmaf(wc, hc, acc);
        acc = fmaf(wd, hd, acc);
    }
    for (; t < cnt; t++) {
        int p = start + t;
        int sa = esrc[p];
        float ea = s2arr[sa] + dval; ea = (ea >= 0.f) ? ea : NEG * ea;
        float ha = __half2float(tab[(size_t)sa * stride + cc]);
        acc = fmaf(__expf(ea - mv) * idv, ha, acc);
    }
    float o = fmaxf(acc + b2[c], 0.f);
    red[t0] = o;
    __syncthreads();
    if (c == 0) {
        float mx = -INFINITY;
        for (int j = 0; j < NCLS; j++) mx = fmaxf(mx, red[g * NCLS + j]);
        float se = 0.f;
        for (int j = 0; j < NCLS; j++) se += __expf(red[g * NCLS + j] - mx);
        gm[g] = mx;
        gl[g] = logf(se);
    }
    __syncthreads();
    out[(size_t)v * NCLS + c] = o - gm[g] - gl[g];
}

// ---------------- launch ----------------

extern "C" void kernel_launch(void* const* d_in, const int* in_sizes, int n_in,
                              void* d_out, int out_size, void* d_ws, size_t ws_size,
                              hipStream_t stream) {
    (void)in_sizes; (void)n_in; (void)out_size; (void)ws_size;
    const float* x   = (const float*)d_in[0];
    const int*   ei  = (const int*)d_in[1];
    const float* W1  = (const float*)d_in[2];
    const float* as1 = (const float*)d_in[3];
    const float* ad1 = (const float*)d_in[4];
    const float* b1  = (const float*)d_in[5];
    const float* W2  = (const float*)d_in[6];
    const float* as2 = (const float*)d_in[7];
    const float* ad2 = (const float*)d_in[8];
    const float* b2  = (const float*)d_in[9];
    float* out = (float*)d_out;
    const int* srcA = ei;
    const int* dstA = ei + N_EDGES;

    char* w = (char*)d_ws;
    size_t off = 0;
    auto alloc = [&](size_t bytes) {
        char* p = w + off;
        off = (off + bytes + 255) & ~(size_t)255;
        return p;
    };
    int* esrc     = (int*)alloc((size_t)ET * 4);
    int* rs       = (int*)alloc((size_t)N_NODES * 4);
    int* deg      = (int*)alloc((size_t)N_NODES * 4);
    // region1: Hm/Sx during build, then h1h (fp16) after sort completes
    char* region1 = alloc((size_t)N_NODES * HID * 4);  // 12.8 MB
    float* s1     = (float*)alloc((size_t)N_NODES * 4);
    float* d1     = (float*)alloc((size_t)N_NODES * 4);
    float* hrb    = (float*)alloc((size_t)N_NODES * HID * 4);
    // region2: tmp during build, then h2a/h2b after kB_sort
    char* region2 = alloc((size_t)N_EDGES * 4 + 1024);  // 12.8 MB
    float* s2     = (float*)alloc((size_t)N_NODES * 4);
    float* d2     = (float*)alloc((size_t)N_NODES * 4);
    float* mS     = (float*)alloc((size_t)N_NODES * 4);
    float* idenS  = (float*)alloc((size_t)N_NODES * 4);
    int* bsums    = (int*)alloc(1024 * 4);
    int* boffs    = (int*)alloc(1024 * 4);

    const int L = NB * NBLK;                  // 611524
    int* Hm = (int*)region1;                  // 2.45 MB
    int* Sx = Hm + ((L + 63) & ~63);          // 2.45 MB
    __half* h1h = (__half*)region1;           // 6.4 MB (after build)
    unsigned int* tmp = (unsigned int*)region2;  // 12.8 MB (build only)
    __half* h2a = (__half*)region2;              // 6.4 MB (after sort)
    __half* h2b = (__half*)(region2 + (size_t)N_NODES * 32 * 2);  // 1.6 MB

    int nb1 = (L + 1023) / 1024;
    hipLaunchKernelGGL(kA_hist, dim3(NBLK), dim3(256), 0, stream, dstA, Hm);
    hipLaunchKernelGGL(k_scan_a, dim3(nb1), dim3(256), 0, stream, Hm, Sx, bsums, L);
    hipLaunchKernelGGL(k_scan_b, dim3(1), dim3(256), 0, stream, bsums, boffs, nb1);
    hipLaunchKernelGGL(k_scan_c, dim3((L + 255) / 256), dim3(256), 0, stream, Sx, boffs, L);
    hipLaunchKernelGGL(kA_scatter, dim3(NBLK), dim3(256), 0, stream, srcA, dstA, Sx, tmp);
    hipLaunchKernelGGL(kB_sort, dim3(NB), dim3(256), 0, stream, tmp, Sx, esrc, rs, deg);

    hipLaunchKernelGGL(k_gemm1, dim3(N_NODES / 8), dim3(256), 0, stream, x, W1, as1, ad1, h1h, s1, d1);
    hipLaunchKernelGGL(k_stats, dim3(N_NODES / 4), dim3(256), 0, stream, rs, deg, esrc, s1, d1, mS, idenS);
    hipLaunchKernelGGL(k_agg1, dim3(N_NODES / 4), dim3(256), 0, stream, rs, deg, esrc, h1h, s1, d1, mS, idenS, b1, hrb);
    hipLaunchKernelGGL(k_gemm2, dim3(N_NODES / 8), dim3(320), 0, stream, hrb, W2, as2, ad2, h2a, h2b, s2, d2);
    hipLaunchKernelGGL(k_stats, dim3(N_NODES / 4), dim3(256), 0, stream, rs, deg, esrc, s2, d2, mS, idenS);
    hipLaunchKernelGGL(k_agg2, dim3(N_NODES / 8), dim3(320), 0, stream, rs, deg, esrc, h2a, h2b, s2, d2, mS, idenS, b2, out);
}

// Round 5
// 504.659 us; speedup vs baseline: 2.2165x; 1.0155x over previous
//
#include <hip/hip_runtime.h>
#include <hip/hip_bf16.h>
#include <hip/hip_fp16.h>
#include <math.h>

#define N_NODES 100000
#define N_EDGES 3200000
#define ET (N_EDGES + N_NODES)
#define F_IN 128
#define HID 32
#define NCLS 40
#define NEG 0.2f

// bucket sort geometry
#define NB 782
#define NBLK 782
#define CHUNK 4096
#define BCAP 6144

// ---------------- Pass A: bucket histogram ----------------
__global__ __launch_bounds__(256) void kA_hist(const int* __restrict__ dst,
                                               int* __restrict__ Hm) {
    __shared__ int hist[NB];
    int t = threadIdx.x, k = blockIdx.x;
    for (int i = t; i < NB; i += 256) hist[i] = 0;
    __syncthreads();
    int base = k * CHUNK;
#pragma unroll
    for (int j = 0; j < CHUNK / 256; j++) {
        int e = base + j * 256 + t;
        if (e < N_EDGES) atomicAdd(&hist[dst[e] >> 7], 1);
    }
    __syncthreads();
    for (int i = t; i < NB; i += 256) Hm[i * NBLK + k] = hist[i];
}

// ---------------- generic exclusive scan ----------------
__global__ void k_scan_a(const int* __restrict__ in, int* __restrict__ out,
                         int* __restrict__ bsums, int L) {
    __shared__ int sd[256];
    int t = threadIdx.x, b = blockIdx.x;
    int base = b * 1024 + t * 4;
    int v0 = 0, v1 = 0, v2 = 0, v3 = 0;
    if (base     < L) v0 = in[base];
    if (base + 1 < L) v1 = in[base + 1];
    if (base + 2 < L) v2 = in[base + 2];
    if (base + 3 < L) v3 = in[base + 3];
    int ts = v0 + v1 + v2 + v3;
    sd[t] = ts;
    __syncthreads();
    for (int off = 1; off < 256; off <<= 1) {
        int xx = (t >= off) ? sd[t - off] : 0;
        __syncthreads();
        sd[t] += xx;
        __syncthreads();
    }
    int ex = sd[t] - ts;
    if (t == 255) bsums[b] = sd[255];
    if (base     < L) out[base]     = ex;
    if (base + 1 < L) out[base + 1] = ex + v0;
    if (base + 2 < L) out[base + 2] = ex + v0 + v1;
    if (base + 3 < L) out[base + 3] = ex + v0 + v1 + v2;
}

__global__ void k_scan_b(const int* __restrict__ bsums, int* __restrict__ boffs, int nb) {
    __shared__ int sd[256];
    int t = threadIdx.x;
    int base = t * 4;
    int v0 = 0, v1 = 0, v2 = 0, v3 = 0;
    if (base     < nb) v0 = bsums[base];
    if (base + 1 < nb) v1 = bsums[base + 1];
    if (base + 2 < nb) v2 = bsums[base + 2];
    if (base + 3 < nb) v3 = bsums[base + 3];
    int ts = v0 + v1 + v2 + v3;
    sd[t] = ts;
    __syncthreads();
    for (int off = 1; off < 256; off <<= 1) {
        int xx = (t >= off) ? sd[t - off] : 0;
        __syncthreads();
        sd[t] += xx;
        __syncthreads();
    }
    int ex = sd[t] - ts;
    if (base     < nb) boffs[base]     = ex;
    if (base + 1 < nb) boffs[base + 1] = ex + v0;
    if (base + 2 < nb) boffs[base + 2] = ex + v0 + v1;
    if (base + 3 < nb) boffs[base + 3] = ex + v0 + v1 + v2;
}

__global__ void k_scan_c(int* __restrict__ out, const int* __restrict__ boffs, int L) {
    int i = blockIdx.x * 256 + threadIdx.x;
    if (i < L) out[i] += boffs[i >> 10];
}

// ---------------- Pass A: scatter into buckets ----------------
__global__ __launch_bounds__(256) void kA_scatter(
    const int* __restrict__ src, const int* __restrict__ dst,
    const int* __restrict__ Sx, unsigned int* __restrict__ tmp) {
    __shared__ int hist[NB];
    __shared__ int lofs[NB];
    __shared__ int cur[NB];
    __shared__ int tsum[256];
    __shared__ unsigned int stage[CHUNK];
    __shared__ int gpos[CHUNK];
    int t = threadIdx.x, k = blockIdx.x;
    for (int i = t; i < NB; i += 256) hist[i] = 0;
    __syncthreads();
    int base = k * CHUNK;
    int myd[16], mys[16];
#pragma unroll
    for (int j = 0; j < 16; j++) {
        int e = base + j * 256 + t;
        myd[j] = (e < N_EDGES) ? dst[e] : -1;
        mys[j] = (e < N_EDGES) ? src[e] : 0;
        if (myd[j] >= 0) atomicAdd(&hist[myd[j] >> 7], 1);
    }
    __syncthreads();
    int i0 = 4 * t;
    int h0 = (i0     < NB) ? hist[i0]     : 0;
    int h1 = (i0 + 1 < NB) ? hist[i0 + 1] : 0;
    int h2 = (i0 + 2 < NB) ? hist[i0 + 2] : 0;
    int h3 = (i0 + 3 < NB) ? hist[i0 + 3] : 0;
    int ts = h0 + h1 + h2 + h3;
    tsum[t] = ts;
    __syncthreads();
    for (int off = 1; off < 256; off <<= 1) {
        int xx = (t >= off) ? tsum[t - off] : 0;
        __syncthreads();
        tsum[t] += xx;
        __syncthreads();
    }
    int ex = tsum[t] - ts;
    if (i0     < NB) { lofs[i0]     = ex;                cur[i0]     = 0; }
    if (i0 + 1 < NB) { lofs[i0 + 1] = ex + h0;           cur[i0 + 1] = 0; }
    if (i0 + 2 < NB) { lofs[i0 + 2] = ex + h0 + h1;      cur[i0 + 2] = 0; }
    if (i0 + 3 < NB) { lofs[i0 + 3] = ex + h0 + h1 + h2; cur[i0 + 3] = 0; }
    __syncthreads();
#pragma unroll
    for (int j = 0; j < 16; j++) {
        if (myd[j] >= 0) {
            int bkt = myd[j] >> 7;
            int slot = lofs[bkt] + atomicAdd(&cur[bkt], 1);
            stage[slot] = ((unsigned int)(myd[j] & 127) << 17) | (unsigned int)mys[j];
            gpos[slot] = Sx[bkt * NBLK + k] + (slot - lofs[bkt]);
        }
    }
    __syncthreads();
    int nvalid = min(CHUNK, N_EDGES - base);
    for (int i = t; i < nvalid; i += 256) tmp[gpos[i]] = stage[i];
}

// ---------------- Pass B: per-bucket counting sort ----------------
__global__ __launch_bounds__(256) void kB_sort(
    const unsigned int* __restrict__ tmp, const int* __restrict__ Sx,
    int* __restrict__ esrc, int* __restrict__ rs, int* __restrict__ deg) {
    __shared__ unsigned int stage[BCAP];
    __shared__ int ordered[BCAP + 128];
    __shared__ int cnt[128], lofs[128], cur[128], sc[128];
    int t = threadIdx.x, b = blockIdx.x;
    int myBase = Sx[b * NBLK];
    int nextBase = (b == NB - 1) ? N_EDGES : Sx[(b + 1) * NBLK];
    int cntE = nextBase - myBase;
    int nNodes = min(128, N_NODES - b * 128);
    if (t < 128) { cnt[t] = 0; cur[t] = 0; }
    __syncthreads();
    for (int i = t; i < cntE; i += 256) {
        unsigned int p = tmp[myBase + i];
        stage[i] = p;
        atomicAdd(&cnt[p >> 17], 1);
    }
    __syncthreads();
    int val = 0;
    if (t < 128) { val = (t < nNodes) ? cnt[t] + 1 : 0; sc[t] = val; }
    __syncthreads();
    for (int off = 1; off < 128; off <<= 1) {
        int xx = 0;
        if (t < 128 && t >= off) xx = sc[t - off];
        __syncthreads();
        if (t < 128) sc[t] += xx;
        __syncthreads();
    }
    if (t < 128) lofs[t] = sc[t] - val;
    __syncthreads();
    if (t < nNodes) ordered[lofs[t]] = b * 128 + t;
    for (int i = t; i < cntE; i += 256) {
        unsigned int p = stage[i];
        int n = p >> 17;
        int slot = lofs[n] + 1 + atomicAdd(&cur[n], 1);
        ordered[slot] = (int)(p & 0x1FFFF);
    }
    __syncthreads();
    int gb = myBase + b * 128;
    int totOut = cntE + nNodes;
    for (int i = t; i < totOut; i += 256) esrc[gb + i] = ordered[i];
    if (t < nNodes) {
        rs[b * 128 + t] = gb + lofs[t];
        deg[b * 128 + t] = cnt[t] + 1;
    }
}

// ---------------- GEMMs ----------------

__global__ __launch_bounds__(256) void k_gemm1(
    const float* __restrict__ x, const float* __restrict__ W1,
    const float* __restrict__ a_s, const float* __restrict__ a_d,
    __half* __restrict__ h1h, float* __restrict__ s1, float* __restrict__ d1) {
    __shared__ float Ws[F_IN * HID];
    __shared__ float xs[8 * F_IN];
    int t = threadIdx.x;
    const float4* W4 = (const float4*)W1;
    float4* Ws4 = (float4*)Ws;
#pragma unroll
    for (int i = 0; i < F_IN * HID / 4 / 256; i++)
        Ws4[t + i * 256] = W4[t + i * 256];
    ((float4*)xs)[t] = ((const float4*)(x + (size_t)blockIdx.x * 8 * F_IN))[t];
    __syncthreads();
    int c = t & 31, g = t >> 5;
    int v = blockIdx.x * 8 + g;
    const float4* xg4 = (const float4*)(xs + g * F_IN);
    float acc = 0.f;
#pragma unroll
    for (int k4 = 0; k4 < F_IN / 4; k4++) {
        float4 xv = xg4[k4];
        int k = k4 * 4;
        acc = fmaf(xv.x, Ws[(k + 0) * HID + c], acc);
        acc = fmaf(xv.y, Ws[(k + 1) * HID + c], acc);
        acc = fmaf(xv.z, Ws[(k + 2) * HID + c], acc);
        acc = fmaf(xv.w, Ws[(k + 3) * HID + c], acc);
    }
    h1h[(size_t)v * HID + c] = __float2half(acc);
    float p = acc * a_s[c];
    float q = acc * a_d[c];
    for (int mm = 16; mm >= 1; mm >>= 1) {
        p += __shfl_xor(p, mm, 32);
        q += __shfl_xor(q, mm, 32);
    }
    if (c == 0) { s1[v] = p; d1[v] = q; }
}

__global__ __launch_bounds__(320) void k_gemm2(
    const float* __restrict__ hr, const float* __restrict__ W2,
    const float* __restrict__ a_s, const float* __restrict__ a_d,
    __half* __restrict__ h2a, __half* __restrict__ h2b,
    float* __restrict__ s2, float* __restrict__ d2) {
    __shared__ float Ws[HID * NCLS];
    __shared__ float rsh[8 * HID];
    __shared__ float red_s[320], red_d[320];
    int t = threadIdx.x;
    ((float4*)Ws)[t] = ((const float4*)W2)[t];
    if (t < 64)
        ((float4*)rsh)[t] = ((const float4*)(hr + (size_t)blockIdx.x * 8 * HID))[t];
    __syncthreads();
    int c = t % NCLS;
    int g = t / NCLS;
    int v = blockIdx.x * 8 + g;
    const float* rrow = rsh + g * HID;
    float acc = 0.f;
#pragma unroll
    for (int k = 0; k < HID; k++)
        acc = fmaf(rrow[k], Ws[k * NCLS + c], acc);
    if (c < 32) h2a[(size_t)v * 32 + c] = __float2half(acc);
    else        h2b[(size_t)v * 8 + (c - 32)] = __float2half(acc);
    red_s[t] = acc * a_s[c];
    red_d[t] = acc * a_d[c];
    __syncthreads();
    if (c == 0) {
        float ss = 0.f, dd = 0.f;
        for (int j = 0; j < NCLS; j++) { ss += red_s[t + j]; dd += red_d[t + j]; }
        s2[v] = ss;
        d2[v] = dd;
    }
}

// ---------------- softmax stats + per-edge weight write ----------------
__global__ __launch_bounds__(256) void k_stats(
    const int* __restrict__ rs, const int* __restrict__ deg, const int* __restrict__ esrc,
    const float* __restrict__ sarr, const float* __restrict__ darr,
    float* __restrict__ wout) {
    int lane = threadIdx.x & 63;
    int v = blockIdx.x * 4 + (threadIdx.x >> 6);
    int start = rs[v];
    int cnt = deg[v];
    float dval = darr[v];
    float m = -INFINITY, den = 0.f;
    for (int t = lane; t < cnt; t += 64) {
        int s = esrc[start + t];
        float e = sarr[s] + dval;
        e = (e >= 0.f) ? e : NEG * e;
        if (e > m) { den *= __expf(m - e); m = e; }
        den += __expf(e - m);
    }
    for (int off = 32; off >= 1; off >>= 1) {
        float mo = __shfl_xor(m, off);
        float dno = __shfl_xor(den, off);
        float M = fmaxf(m, mo);
        float wa = (m == -INFINITY) ? 0.f : __expf(m - M);
        float wb = (mo == -INFINITY) ? 0.f : __expf(mo - M);
        den = den * wa + dno * wb;
        m = M;
    }
    // all lanes now hold total (m, den); write normalized weights coalesced
    float iden = 1.f / den;
    for (int t = lane; t < cnt; t += 64) {
        int s = esrc[start + t];
        float e = sarr[s] + dval;
        e = (e >= 0.f) ? e : NEG * e;
        wout[start + t] = __expf(e - m) * iden;
    }
}

// ---------------- aggregation, layer 1: pure weighted gather (half2) ----------------
// wave per node; 4 edges x 16 half2-lanes
__global__ __launch_bounds__(256) void k_agg1(
    const int* __restrict__ rs, const int* __restrict__ deg, const int* __restrict__ esrc,
    const __half2* __restrict__ h1t, const float* __restrict__ wbuf,
    const float* __restrict__ b1, float* __restrict__ hr) {
    int lane = threadIdx.x & 63;
    int v = blockIdx.x * 4 + (threadIdx.x >> 6);
    int c2 = lane & 15;
    int esub = lane >> 4;  // 0..3
    int start = rs[v];
    int cnt = deg[v];
    float ax = 0.f, ay = 0.f;
    int t = esub;
    for (; t + 7 < cnt; t += 8) {
        int p = start + t;
        int sa = esrc[p];
        int sb = esrc[p + 4];
        float wa = wbuf[p];
        float wb = wbuf[p + 4];
        float2 fa = __half22float2(h1t[(size_t)sa * 16 + c2]);
        float2 fb = __half22float2(h1t[(size_t)sb * 16 + c2]);
        ax = fmaf(wa, fa.x, ax);
        ay = fmaf(wa, fa.y, ay);
        ax = fmaf(wb, fb.x, ax);
        ay = fmaf(wb, fb.y, ay);
    }
    for (; t < cnt; t += 4) {
        int p = start + t;
        int sa = esrc[p];
        float wa = wbuf[p];
        float2 fa = __half22float2(h1t[(size_t)sa * 16 + c2]);
        ax = fmaf(wa, fa.x, ax);
        ay = fmaf(wa, fa.y, ay);
    }
    ax += __shfl_xor(ax, 16); ay += __shfl_xor(ay, 16);
    ax += __shfl_xor(ax, 32); ay += __shfl_xor(ay, 32);
    if (esub == 0) {
        float2 o;
        o.x = fmaxf(ax + b1[2 * c2], 0.f);
        o.y = fmaxf(ay + b1[2 * c2 + 1], 0.f);
        ((float2*)(hr + (size_t)v * HID))[c2] = o;
    }
}

// ---------------- aggregation, layer 2: weighted gather (half2) + log_softmax ----------------
// 8 nodes/block of 320; per node 40 threads = 2 edges x 20 half2-lanes
__global__ __launch_bounds__(320) void k_agg2(
    const int* __restrict__ rs, const int* __restrict__ deg, const int* __restrict__ esrc,
    const __half2* __restrict__ h2a, const __half2* __restrict__ h2b,
    const float* __restrict__ wbuf,
    const float* __restrict__ b2, float* __restrict__ out) {
    __shared__ float redx[320], redy[320];
    __shared__ float onx[8][20], ony[8][20];
    __shared__ float gm[8], gl[8];
    int t0 = threadIdx.x;
    int g = t0 / 40;
    int tn = t0 % 40;
    int c2 = tn % 20;
    int esub = tn / 20;  // 0,1
    int v = blockIdx.x * 8 + g;
    int start = rs[v];
    int cnt = deg[v];
    const __half2* tab;
    int stride, cc;
    if (c2 < 16) { tab = h2a; stride = 16; cc = c2; }
    else         { tab = h2b; stride = 4;  cc = c2 - 16; }
    float ax = 0.f, ay = 0.f;
    int t = esub;
    for (; t + 3 < cnt; t += 4) {
        int p = start + t;
        int sa = esrc[p];
        int sb = esrc[p + 2];
        float wa = wbuf[p];
        float wb = wbuf[p + 2];
        float2 fa = __half22float2(tab[(size_t)sa * stride + cc]);
        float2 fb = __half22float2(tab[(size_t)sb * stride + cc]);
        ax = fmaf(wa, fa.x, ax);
        ay = fmaf(wa, fa.y, ay);
        ax = fmaf(wb, fb.x, ax);
        ay = fmaf(wb, fb.y, ay);
    }
    for (; t < cnt; t += 2) {
        int p = start + t;
        int sa = esrc[p];
        float wa = wbuf[p];
        float2 fa = __half22float2(tab[(size_t)sa * stride + cc]);
        ax = fmaf(wa, fa.x, ax);
        ay = fmaf(wa, fa.y, ay);
    }
    redx[t0] = ax;
    redy[t0] = ay;
    __syncthreads();
    float ox = 0.f, oy = 0.f;
    if (esub == 0) {
        ox = fmaxf(ax + redx[t0 + 20] + b2[2 * c2], 0.f);
        oy = fmaxf(ay + redy[t0 + 20] + b2[2 * c2 + 1], 0.f);
        onx[g][c2] = ox;
        ony[g][c2] = oy;
    }
    __syncthreads();
    if (esub == 0 && c2 == 0) {
        float mx = -INFINITY;
        for (int j = 0; j < 20; j++) {
            mx = fmaxf(mx, onx[g][j]);
            mx = fmaxf(mx, ony[g][j]);
        }
        float se = 0.f;
        for (int j = 0; j < 20; j++) {
            se += __expf(onx[g][j] - mx);
            se += __expf(ony[g][j] - mx);
        }
        gm[g] = mx;
        gl[g] = logf(se);
    }
    __syncthreads();
    if (esub == 0) {
        float corr = gm[g] + gl[g];
        float2 o2;
        o2.x = ox - corr;
        o2.y = oy - corr;
        ((float2*)(out + (size_t)v * NCLS))[c2] = o2;
    }
}

// ---------------- launch ----------------

extern "C" void kernel_launch(void* const* d_in, const int* in_sizes, int n_in,
                              void* d_out, int out_size, void* d_ws, size_t ws_size,
                              hipStream_t stream) {
    (void)in_sizes; (void)n_in; (void)out_size; (void)ws_size;
    const float* x   = (const float*)d_in[0];
    const int*   ei  = (const int*)d_in[1];
    const float* W1  = (const float*)d_in[2];
    const float* as1 = (const float*)d_in[3];
    const float* ad1 = (const float*)d_in[4];
    const float* b1  = (const float*)d_in[5];
    const float* W2  = (const float*)d_in[6];
    const float* as2 = (const float*)d_in[7];
    const float* ad2 = (const float*)d_in[8];
    const float* b2  = (const float*)d_in[9];
    float* out = (float*)d_out;
    const int* srcA = ei;
    const int* dstA = ei + N_EDGES;

    char* w = (char*)d_ws;
    size_t off = 0;
    auto alloc = [&](size_t bytes) {
        char* p = w + off;
        off = (off + bytes + 255) & ~(size_t)255;
        return p;
    };
    int* esrc     = (int*)alloc((size_t)ET * 4);
    int* rs       = (int*)alloc((size_t)N_NODES * 4);
    int* deg      = (int*)alloc((size_t)N_NODES * 4);
    char* region1 = alloc((size_t)N_NODES * HID * 4);   // Hm/Sx then h1h
    float* s1     = (float*)alloc((size_t)N_NODES * 4);
    float* d1     = (float*)alloc((size_t)N_NODES * 4);
    float* hrb    = (float*)alloc((size_t)N_NODES * HID * 4);
    char* region2 = alloc((size_t)N_EDGES * 4 + 1024);  // tmp then h2a/h2b
    float* s2     = (float*)alloc((size_t)N_NODES * 4);
    float* d2     = (float*)alloc((size_t)N_NODES * 4);
    float* wbuf   = (float*)alloc((size_t)ET * 4);      // per-edge weights (reused both layers)
    int* bsums    = (int*)alloc(1024 * 4);
    int* boffs    = (int*)alloc(1024 * 4);

    const int L = NB * NBLK;
    int* Hm = (int*)region1;
    int* Sx = Hm + ((L + 63) & ~63);
    __half* h1h = (__half*)region1;
    unsigned int* tmp = (unsigned int*)region2;
    __half* h2a = (__half*)region2;
    __half* h2b = (__half*)(region2 + (size_t)N_NODES * 32 * 2);

    int nb1 = (L + 1023) / 1024;
    hipLaunchKernelGGL(kA_hist, dim3(NBLK), dim3(256), 0, stream, dstA, Hm);
    hipLaunchKernelGGL(k_scan_a, dim3(nb1), dim3(256), 0, stream, Hm, Sx, bsums, L);
    hipLaunchKernelGGL(k_scan_b, dim3(1), dim3(256), 0, stream, bsums, boffs, nb1);
    hipLaunchKernelGGL(k_scan_c, dim3((L + 255) / 256), dim3(256), 0, stream, Sx, boffs, L);
    hipLaunchKernelGGL(kA_scatter, dim3(NBLK), dim3(256), 0, stream, srcA, dstA, Sx, tmp);
    hipLaunchKernelGGL(kB_sort, dim3(NB), dim3(256), 0, stream, tmp, Sx, esrc, rs, deg);

    hipLaunchKernelGGL(k_gemm1, dim3(N_NODES / 8), dim3(256), 0, stream, x, W1, as1, ad1, h1h, s1, d1);
    hipLaunchKernelGGL(k_stats, dim3(N_NODES / 4), dim3(256), 0, stream, rs, deg, esrc, s1, d1, wbuf);
    hipLaunchKernelGGL(k_agg1, dim3(N_NODES / 4), dim3(256), 0, stream, rs, deg, esrc,
                       (const __half2*)h1h, wbuf, b1, hrb);
    hipLaunchKernelGGL(k_gemm2, dim3(N_NODES / 8), dim3(320), 0, stream, hrb, W2, as2, ad2, h2a, h2b, s2, d2);
    hipLaunchKernelGGL(k_stats, dim3(N_NODES / 4), dim3(256), 0, stream, rs, deg, esrc, s2, d2, wbuf);
    hipLaunchKernelGGL(k_agg2, dim3(N_NODES / 8), dim3(320), 0, stream, rs, deg, esrc,
                       (const __half2*)h2a, (const __half2*)h2b, wbuf, b2, out);
}

// Round 6
// 419.879 us; speedup vs baseline: 2.6640x; 1.2019x over previous
//
#include <hip/hip_runtime.h>
#include <hip/hip_bf16.h>
#include <hip/hip_fp16.h>
#include <math.h>

#define N_NODES 100000
#define N_EDGES 3200000
#define ET (N_EDGES + N_NODES)
#define F_IN 128
#define HID 32
#define NCLS 40
#define NEG 0.2f

// bucket sort geometry
#define NB 782
#define NBLK 782
#define CHUNK 4096
#define BCAP 6144

// ---------------- Pass A: bucket histogram ----------------
__global__ __launch_bounds__(256) void kA_hist(const int* __restrict__ dst,
                                               int* __restrict__ Hm) {
    __shared__ int hist[NB];
    int t = threadIdx.x, k = blockIdx.x;
    for (int i = t; i < NB; i += 256) hist[i] = 0;
    __syncthreads();
    int base = k * CHUNK;
#pragma unroll
    for (int j = 0; j < CHUNK / 256; j++) {
        int e = base + j * 256 + t;
        if (e < N_EDGES) atomicAdd(&hist[dst[e] >> 7], 1);
    }
    __syncthreads();
    for (int i = t; i < NB; i += 256) Hm[i * NBLK + k] = hist[i];
}

// ---------------- generic exclusive scan ----------------
__global__ void k_scan_a(const int* __restrict__ in, int* __restrict__ out,
                         int* __restrict__ bsums, int L) {
    __shared__ int sd[256];
    int t = threadIdx.x, b = blockIdx.x;
    int base = b * 1024 + t * 4;
    int v0 = 0, v1 = 0, v2 = 0, v3 = 0;
    if (base     < L) v0 = in[base];
    if (base + 1 < L) v1 = in[base + 1];
    if (base + 2 < L) v2 = in[base + 2];
    if (base + 3 < L) v3 = in[base + 3];
    int ts = v0 + v1 + v2 + v3;
    sd[t] = ts;
    __syncthreads();
    for (int off = 1; off < 256; off <<= 1) {
        int xx = (t >= off) ? sd[t - off] : 0;
        __syncthreads();
        sd[t] += xx;
        __syncthreads();
    }
    int ex = sd[t] - ts;
    if (t == 255) bsums[b] = sd[255];
    if (base     < L) out[base]     = ex;
    if (base + 1 < L) out[base + 1] = ex + v0;
    if (base + 2 < L) out[base + 2] = ex + v0 + v1;
    if (base + 3 < L) out[base + 3] = ex + v0 + v1 + v2;
}

__global__ void k_scan_b(const int* __restrict__ bsums, int* __restrict__ boffs, int nb) {
    __shared__ int sd[256];
    int t = threadIdx.x;
    int base = t * 4;
    int v0 = 0, v1 = 0, v2 = 0, v3 = 0;
    if (base     < nb) v0 = bsums[base];
    if (base + 1 < nb) v1 = bsums[base + 1];
    if (base + 2 < nb) v2 = bsums[base + 2];
    if (base + 3 < nb) v3 = bsums[base + 3];
    int ts = v0 + v1 + v2 + v3;
    sd[t] = ts;
    __syncthreads();
    for (int off = 1; off < 256; off <<= 1) {
        int xx = (t >= off) ? sd[t - off] : 0;
        __syncthreads();
        sd[t] += xx;
        __syncthreads();
    }
    int ex = sd[t] - ts;
    if (base     < nb) boffs[base]     = ex;
    if (base + 1 < nb) boffs[base + 1] = ex + v0;
    if (base + 2 < nb) boffs[base + 2] = ex + v0 + v1;
    if (base + 3 < nb) boffs[base + 3] = ex + v0 + v1 + v2;
}

__global__ void k_scan_c(int* __restrict__ out, const int* __restrict__ boffs, int L) {
    int i = blockIdx.x * 256 + threadIdx.x;
    if (i < L) out[i] += boffs[i >> 10];
}

// ---------------- Pass A: scatter into buckets ----------------
__global__ __launch_bounds__(256) void kA_scatter(
    const int* __restrict__ src, const int* __restrict__ dst,
    const int* __restrict__ Sx, unsigned int* __restrict__ tmp) {
    __shared__ int hist[NB];
    __shared__ int lofs[NB];
    __shared__ int cur[NB];
    __shared__ int tsum[256];
    __shared__ unsigned int stage[CHUNK];
    __shared__ int gpos[CHUNK];
    int t = threadIdx.x, k = blockIdx.x;
    for (int i = t; i < NB; i += 256) hist[i] = 0;
    __syncthreads();
    int base = k * CHUNK;
    int myd[16], mys[16];
#pragma unroll
    for (int j = 0; j < 16; j++) {
        int e = base + j * 256 + t;
        myd[j] = (e < N_EDGES) ? dst[e] : -1;
        mys[j] = (e < N_EDGES) ? src[e] : 0;
        if (myd[j] >= 0) atomicAdd(&hist[myd[j] >> 7], 1);
    }
    __syncthreads();
    int i0 = 4 * t;
    int h0 = (i0     < NB) ? hist[i0]     : 0;
    int h1 = (i0 + 1 < NB) ? hist[i0 + 1] : 0;
    int h2 = (i0 + 2 < NB) ? hist[i0 + 2] : 0;
    int h3 = (i0 + 3 < NB) ? hist[i0 + 3] : 0;
    int ts = h0 + h1 + h2 + h3;
    tsum[t] = ts;
    __syncthreads();
    for (int off = 1; off < 256; off <<= 1) {
        int xx = (t >= off) ? tsum[t - off] : 0;
        __syncthreads();
        tsum[t] += xx;
        __syncthreads();
    }
    int ex = tsum[t] - ts;
    if (i0     < NB) { lofs[i0]     = ex;                cur[i0]     = 0; }
    if (i0 + 1 < NB) { lofs[i0 + 1] = ex + h0;           cur[i0 + 1] = 0; }
    if (i0 + 2 < NB) { lofs[i0 + 2] = ex + h0 + h1;      cur[i0 + 2] = 0; }
    if (i0 + 3 < NB) { lofs[i0 + 3] = ex + h0 + h1 + h2; cur[i0 + 3] = 0; }
    __syncthreads();
#pragma unroll
    for (int j = 0; j < 16; j++) {
        if (myd[j] >= 0) {
            int bkt = myd[j] >> 7;
            int slot = lofs[bkt] + atomicAdd(&cur[bkt], 1);
            stage[slot] = ((unsigned int)(myd[j] & 127) << 17) | (unsigned int)mys[j];
            gpos[slot] = Sx[bkt * NBLK + k] + (slot - lofs[bkt]);
        }
    }
    __syncthreads();
    int nvalid = min(CHUNK, N_EDGES - base);
    for (int i = t; i < nvalid; i += 256) tmp[gpos[i]] = stage[i];
}

// ---------------- Pass B: per-bucket counting sort ----------------
__global__ __launch_bounds__(256) void kB_sort(
    const unsigned int* __restrict__ tmp, const int* __restrict__ Sx,
    int* __restrict__ esrc, int* __restrict__ rs, int* __restrict__ deg) {
    __shared__ unsigned int stage[BCAP];
    __shared__ int ordered[BCAP + 128];
    __shared__ int cnt[128], lofs[128], cur[128], sc[128];
    int t = threadIdx.x, b = blockIdx.x;
    int myBase = Sx[b * NBLK];
    int nextBase = (b == NB - 1) ? N_EDGES : Sx[(b + 1) * NBLK];
    int cntE = nextBase - myBase;
    int nNodes = min(128, N_NODES - b * 128);
    if (t < 128) { cnt[t] = 0; cur[t] = 0; }
    __syncthreads();
    for (int i = t; i < cntE; i += 256) {
        unsigned int p = tmp[myBase + i];
        stage[i] = p;
        atomicAdd(&cnt[p >> 17], 1);
    }
    __syncthreads();
    int val = 0;
    if (t < 128) { val = (t < nNodes) ? cnt[t] + 1 : 0; sc[t] = val; }
    __syncthreads();
    for (int off = 1; off < 128; off <<= 1) {
        int xx = 0;
        if (t < 128 && t >= off) xx = sc[t - off];
        __syncthreads();
        if (t < 128) sc[t] += xx;
        __syncthreads();
    }
    if (t < 128) lofs[t] = sc[t] - val;
    __syncthreads();
    if (t < nNodes) ordered[lofs[t]] = b * 128 + t;
    for (int i = t; i < cntE; i += 256) {
        unsigned int p = stage[i];
        int n = p >> 17;
        int slot = lofs[n] + 1 + atomicAdd(&cur[n], 1);
        ordered[slot] = (int)(p & 0x1FFFF);
    }
    __syncthreads();
    int gb = myBase + b * 128;
    int totOut = cntE + nNodes;
    for (int i = t; i < totOut; i += 256) esrc[gb + i] = ordered[i];
    if (t < nNodes) {
        rs[b * 128 + t] = gb + lofs[t];
        deg[b * 128 + t] = cnt[t] + 1;
    }
}

// ---------------- prep: va_s = W2 @ att_src2, va_d = W2 @ att_dst2 ----------------
__global__ void k_prep(const float* __restrict__ W2, const float* __restrict__ as2,
                       const float* __restrict__ ad2,
                       float* __restrict__ va_s, float* __restrict__ va_d) {
    int k = threadIdx.x;
    if (k < HID) {
        float ps = 0.f, pd = 0.f;
        for (int c = 0; c < NCLS; c++) {
            float w = W2[k * NCLS + c];
            ps = fmaf(w, as2[c], ps);
            pd = fmaf(w, ad2[c], pd);
        }
        va_s[k] = ps;
        va_d[k] = pd;
    }
}

// ---------------- GEMM1: h1(fp16) = x @ W1 ; s1,d1 fp32 ----------------
__global__ __launch_bounds__(256) void k_gemm1(
    const float* __restrict__ x, const float* __restrict__ W1,
    const float* __restrict__ a_s, const float* __restrict__ a_d,
    __half* __restrict__ h1h, float* __restrict__ s1, float* __restrict__ d1) {
    __shared__ float Ws[F_IN * HID];
    __shared__ float xs[8 * F_IN];
    int t = threadIdx.x;
    const float4* W4 = (const float4*)W1;
    float4* Ws4 = (float4*)Ws;
#pragma unroll
    for (int i = 0; i < F_IN * HID / 4 / 256; i++)
        Ws4[t + i * 256] = W4[t + i * 256];
    ((float4*)xs)[t] = ((const float4*)(x + (size_t)blockIdx.x * 8 * F_IN))[t];
    __syncthreads();
    int c = t & 31, g = t >> 5;
    int v = blockIdx.x * 8 + g;
    const float4* xg4 = (const float4*)(xs + g * F_IN);
    float acc = 0.f;
#pragma unroll
    for (int k4 = 0; k4 < F_IN / 4; k4++) {
        float4 xv = xg4[k4];
        int k = k4 * 4;
        acc = fmaf(xv.x, Ws[(k + 0) * HID + c], acc);
        acc = fmaf(xv.y, Ws[(k + 1) * HID + c], acc);
        acc = fmaf(xv.z, Ws[(k + 2) * HID + c], acc);
        acc = fmaf(xv.w, Ws[(k + 3) * HID + c], acc);
    }
    h1h[(size_t)v * HID + c] = __float2half(acc);
    float p = acc * a_s[c];
    float q = acc * a_d[c];
    for (int mm = 16; mm >= 1; mm >>= 1) {
        p += __shfl_xor(p, mm, 32);
        q += __shfl_xor(q, mm, 32);
    }
    if (c == 0) { s1[v] = p; d1[v] = q; }
}

// ---------------- stats: single pass, unnormalized weights + 1/den ----------------
__global__ __launch_bounds__(256) void k_stats(
    const int* __restrict__ rs, const int* __restrict__ deg, const int* __restrict__ esrc,
    const float* __restrict__ sarr, const float* __restrict__ darr,
    float* __restrict__ wout, float* __restrict__ idenS) {
    int lane = threadIdx.x & 63;
    int v = blockIdx.x * 4 + (threadIdx.x >> 6);
    int start = rs[v];
    int cnt = deg[v];
    float dval = darr[v];
    float den = 0.f;
    for (int t = lane; t < cnt; t += 64) {
        int s = esrc[start + t];
        float e = sarr[s] + dval;
        e = (e >= 0.f) ? e : NEG * e;
        float w = __expf(e);   // logits are O(+-7): exp safe in fp32, no max needed
        wout[start + t] = w;
        den += w;
    }
    for (int off = 32; off >= 1; off >>= 1) den += __shfl_xor(den, off);
    if (lane == 0) idenS[v] = 1.f / den;
}

// ---------------- agg1: weighted gather of h1 (fp16), writes hr fp16 + fused s2,d2 ----
// wave per node; 16 half2-lanes x 4 edge slots; 4-deep chain unroll
__global__ __launch_bounds__(256) void k_agg1(
    const int* __restrict__ rs, const int* __restrict__ deg, const int* __restrict__ esrc,
    const __half2* __restrict__ h1t, const float* __restrict__ wbuf,
    const float* __restrict__ idenS, const float* __restrict__ b1,
    const float* __restrict__ va_s, const float* __restrict__ va_d,
    __half2* __restrict__ hrt, float* __restrict__ s2, float* __restrict__ d2) {
    int lane = threadIdx.x & 63;
    int v = blockIdx.x * 4 + (threadIdx.x >> 6);
    int c2 = lane & 15;
    int esub = lane >> 4;  // 0..3
    int start = rs[v];
    int cnt = deg[v];
    float ax = 0.f, ay = 0.f;
    int t = esub;
    for (; t + 12 < cnt; t += 16) {
        int p = start + t;
        int sa = esrc[p];
        int sb = esrc[p + 4];
        int sc = esrc[p + 8];
        int sd = esrc[p + 12];
        float wa = wbuf[p];
        float wb = wbuf[p + 4];
        float wc = wbuf[p + 8];
        float wd = wbuf[p + 12];
        float2 fa = __half22float2(h1t[(size_t)sa * 16 + c2]);
        float2 fb = __half22float2(h1t[(size_t)sb * 16 + c2]);
        float2 fc = __half22float2(h1t[(size_t)sc * 16 + c2]);
        float2 fd = __half22float2(h1t[(size_t)sd * 16 + c2]);
        ax = fmaf(wa, fa.x, ax); ay = fmaf(wa, fa.y, ay);
        ax = fmaf(wb, fb.x, ax); ay = fmaf(wb, fb.y, ay);
        ax = fmaf(wc, fc.x, ax); ay = fmaf(wc, fc.y, ay);
        ax = fmaf(wd, fd.x, ax); ay = fmaf(wd, fd.y, ay);
    }
    for (; t < cnt; t += 4) {
        int p = start + t;
        int sa = esrc[p];
        float wa = wbuf[p];
        float2 fa = __half22float2(h1t[(size_t)sa * 16 + c2]);
        ax = fmaf(wa, fa.x, ax);
        ay = fmaf(wa, fa.y, ay);
    }
    ax += __shfl_xor(ax, 16); ay += __shfl_xor(ay, 16);
    ax += __shfl_xor(ax, 32); ay += __shfl_xor(ay, 32);
    if (esub == 0) {
        float iden = idenS[v];
        float ox = fmaxf(ax * iden + b1[2 * c2], 0.f);
        float oy = fmaxf(ay * iden + b1[2 * c2 + 1], 0.f);
        hrt[(size_t)v * 16 + c2] = __floats2half2_rn(ox, oy);
        // fused s2,d2: s2[v] = hr[v] . (W2@as2)
        float p_ = ox * va_s[2 * c2] + oy * va_s[2 * c2 + 1];
        float q_ = ox * va_d[2 * c2] + oy * va_d[2 * c2 + 1];
        for (int mm = 8; mm >= 1; mm >>= 1) {
            p_ += __shfl_xor(p_, mm);
            q_ += __shfl_xor(q_, mm);
        }
        if (c2 == 0) { s2[v] = p_; d2[v] = q_; }
    }
}

// ---------------- agg2: weighted gather of hr (fp16), epilogue @W2 + log_softmax ----
// wave per node; same gather geometry as agg1; per-node 32x40 GEMV epilogue
__global__ __launch_bounds__(256) void k_agg2(
    const int* __restrict__ rs, const int* __restrict__ deg, const int* __restrict__ esrc,
    const __half2* __restrict__ hrt, const float* __restrict__ wbuf,
    const float* __restrict__ idenS, const float* __restrict__ W2,
    const float* __restrict__ b2, float* __restrict__ out) {
    __shared__ float W2s[HID * NCLS];   // 5 KB
    __shared__ float hragg[4][HID];
    int tid = threadIdx.x;
    for (int i = tid; i < HID * NCLS; i += 256) W2s[i] = W2[i];
    __syncthreads();
    int lane = tid & 63;
    int wid = tid >> 6;
    int v = blockIdx.x * 4 + wid;
    int c2 = lane & 15;
    int esub = lane >> 4;
    int start = rs[v];
    int cnt = deg[v];
    float ax = 0.f, ay = 0.f;
    int t = esub;
    for (; t + 12 < cnt; t += 16) {
        int p = start + t;
        int sa = esrc[p];
        int sb = esrc[p + 4];
        int sc = esrc[p + 8];
        int sd = esrc[p + 12];
        float wa = wbuf[p];
        float wb = wbuf[p + 4];
        float wc = wbuf[p + 8];
        float wd = wbuf[p + 12];
        float2 fa = __half22float2(hrt[(size_t)sa * 16 + c2]);
        float2 fb = __half22float2(hrt[(size_t)sb * 16 + c2]);
        float2 fc = __half22float2(hrt[(size_t)sc * 16 + c2]);
        float2 fd = __half22float2(hrt[(size_t)sd * 16 + c2]);
        ax = fmaf(wa, fa.x, ax); ay = fmaf(wa, fa.y, ay);
        ax = fmaf(wb, fb.x, ax); ay = fmaf(wb, fb.y, ay);
        ax = fmaf(wc, fc.x, ax); ay = fmaf(wc, fc.y, ay);
        ax = fmaf(wd, fd.x, ax); ay = fmaf(wd, fd.y, ay);
    }
    for (; t < cnt; t += 4) {
        int p = start + t;
        int sa = esrc[p];
        float wa = wbuf[p];
        float2 fa = __half22float2(hrt[(size_t)sa * 16 + c2]);
        ax = fmaf(wa, fa.x, ax);
        ay = fmaf(wa, fa.y, ay);
    }
    ax += __shfl_xor(ax, 16); ay += __shfl_xor(ay, 16);
    ax += __shfl_xor(ax, 32); ay += __shfl_xor(ay, 32);
    if (esub == 0) {
        float iden = idenS[v];
        hragg[wid][2 * c2] = ax * iden;
        hragg[wid][2 * c2 + 1] = ay * iden;
    }
    __syncthreads();
    // epilogue: z = hragg @ W2 + b2 ; relu ; log_softmax over 40 classes
    float z = 0.f;
    if (lane < NCLS) {
#pragma unroll
        for (int k = 0; k < HID; k++)
            z = fmaf(hragg[wid][k], W2s[k * NCLS + lane], z);
        z = fmaxf(z + b2[lane], 0.f);
    }
    float mz = (lane < NCLS) ? z : -INFINITY;
    for (int mm = 32; mm >= 1; mm >>= 1) mz = fmaxf(mz, __shfl_xor(mz, mm));
    float ex = (lane < NCLS) ? __expf(z - mz) : 0.f;
    float se = ex;
    for (int mm = 32; mm >= 1; mm >>= 1) se += __shfl_xor(se, mm);
    if (lane < NCLS) out[(size_t)v * NCLS + lane] = z - mz - logf(se);
}

// ---------------- launch ----------------

extern "C" void kernel_launch(void* const* d_in, const int* in_sizes, int n_in,
                              void* d_out, int out_size, void* d_ws, size_t ws_size,
                              hipStream_t stream) {
    (void)in_sizes; (void)n_in; (void)out_size; (void)ws_size;
    const float* x   = (const float*)d_in[0];
    const int*   ei  = (const int*)d_in[1];
    const float* W1  = (const float*)d_in[2];
    const float* as1 = (const float*)d_in[3];
    const float* ad1 = (const float*)d_in[4];
    const float* b1  = (const float*)d_in[5];
    const float* W2  = (const float*)d_in[6];
    const float* as2 = (const float*)d_in[7];
    const float* ad2 = (const float*)d_in[8];
    const float* b2  = (const float*)d_in[9];
    float* out = (float*)d_out;
    const int* srcA = ei;
    const int* dstA = ei + N_EDGES;

    char* w = (char*)d_ws;
    size_t off = 0;
    auto alloc = [&](size_t bytes) {
        char* p = w + off;
        off = (off + bytes + 255) & ~(size_t)255;
        return p;
    };
    int* esrc     = (int*)alloc((size_t)ET * 4);
    int* rs       = (int*)alloc((size_t)N_NODES * 4);
    int* deg      = (int*)alloc((size_t)N_NODES * 4);
    char* region1 = alloc((size_t)N_NODES * HID * 4);   // Hm/Sx during build, then h1h
    float* s1     = (float*)alloc((size_t)N_NODES * 4);
    float* d1     = (float*)alloc((size_t)N_NODES * 4);
    __half* hrt   = (__half*)alloc((size_t)N_NODES * HID * 2);  // hr fp16 table
    char* region2 = alloc((size_t)N_EDGES * 4 + 1024);  // tmp (build only)
    float* s2     = (float*)alloc((size_t)N_NODES * 4);
    float* d2     = (float*)alloc((size_t)N_NODES * 4);
    float* wbuf   = (float*)alloc((size_t)ET * 4);      // per-edge weights
    float* idenS  = (float*)alloc((size_t)N_NODES * 4);
    float* va_s   = (float*)alloc(HID * 4);
    float* va_d   = (float*)alloc(HID * 4);
    int* bsums    = (int*)alloc(1024 * 4);
    int* boffs    = (int*)alloc(1024 * 4);

    const int L = NB * NBLK;
    int* Hm = (int*)region1;
    int* Sx = Hm + ((L + 63) & ~63);
    __half* h1h = (__half*)region1;
    unsigned int* tmp = (unsigned int*)region2;

    int nb1 = (L + 1023) / 1024;
    hipLaunchKernelGGL(kA_hist, dim3(NBLK), dim3(256), 0, stream, dstA, Hm);
    hipLaunchKernelGGL(k_scan_a, dim3(nb1), dim3(256), 0, stream, Hm, Sx, bsums, L);
    hipLaunchKernelGGL(k_scan_b, dim3(1), dim3(256), 0, stream, bsums, boffs, nb1);
    hipLaunchKernelGGL(k_scan_c, dim3((L + 255) / 256), dim3(256), 0, stream, Sx, boffs, L);
    hipLaunchKernelGGL(kA_scatter, dim3(NBLK), dim3(256), 0, stream, srcA, dstA, Sx, tmp);
    hipLaunchKernelGGL(kB_sort, dim3(NB), dim3(256), 0, stream, tmp, Sx, esrc, rs, deg);

    hipLaunchKernelGGL(k_prep, dim3(1), dim3(64), 0, stream, W2, as2, ad2, va_s, va_d);
    hipLaunchKernelGGL(k_gemm1, dim3(N_NODES / 8), dim3(256), 0, stream, x, W1, as1, ad1, h1h, s1, d1);
    hipLaunchKernelGGL(k_stats, dim3(N_NODES / 4), dim3(256), 0, stream, rs, deg, esrc, s1, d1, wbuf, idenS);
    hipLaunchKernelGGL(k_agg1, dim3(N_NODES / 4), dim3(256), 0, stream, rs, deg, esrc,
                       (const __half2*)h1h, wbuf, idenS, b1, va_s, va_d,
                       (__half2*)hrt, s2, d2);
    hipLaunchKernelGGL(k_stats, dim3(N_NODES / 4), dim3(256), 0, stream, rs, deg, esrc, s2, d2, wbuf, idenS);
    hipLaunchKernelGGL(k_agg2, dim3(N_NODES / 4), dim3(256), 0, stream, rs, deg, esrc,
                       (const __half2*)hrt, wbuf, idenS, W2, b2, out);
}